// Round 2
// baseline (1463.550 us; speedup 1.0000x reference)
//
#include <hip/hip_runtime.h>
#include <math.h>

// ---------------------------------------------------------------------------
// GP posterior mean:
//   k_outer : separable NUFFT outer products, fp32 atomic-free partials.
//   k_reduce: partials -> fp32 circulant table vcf + fp64 rhs b.
//   k_cg_solve: R15: twiddle de-LDS-ification.
//     - bfly16 twiddles are lane-uniform exp(-i*pi*k/8) -> compile-time
//       constants (kills ~43k LDS reads/iter).
//     - All CG-loop bflyA calls share b = tid&15 -> 7 f2 twiddles hoisted
//       to registers (kills another ~43k LDS reads/iter).
//     - Vf is iteration-invariant -> 16 f2 hoisted to regs (kills 16 L2
//       loads/thread in the longest phase).
//     - amdgpu_waves_per_eu(4,4): single 16-wave block => 4 waves/EU is
//       the only possible occupancy; unlock the full 128-VGPR budget
//       (VGPR_Count=64 showed the compiler was spilling for 8 w/EU).
//     - i_colA stores only rows<64 (only corner consumed downstream).
//     R14: CG-state remap (thread owns row tid>>4, cols (tid&15)+16s);
//     fused scatter+rowA and i_rowA+Ap; x in regs. 8 barriers/iter.
//     R12 lesson kept: scalar cmul + 2 separate reduces.
//   k_eval  : posterior mean at test points from al = ws*x_50.
// ---------------------------------------------------------------------------

typedef float f2 __attribute__((ext_vector_type(2)));
#define PB 16
#define RS 137          // Z row stride in f2 (8 blocks x 17)

__device__ inline f2 f2s(float s) { return (f2){s, s}; }
__device__ inline f2 cmulf(f2 a, f2 b) {   // a*b
    return (f2){a.x * b.x - a.y * b.y, a.x * b.y + a.y * b.x};
}
__device__ inline f2 cmulcf(f2 a, f2 b) {  // a*conj(b)
    return (f2){a.x * b.x + a.y * b.y, a.y * b.x - a.x * b.y};
}
__device__ inline int cpad(int c) { return (c >> 4) * 17 + (c & 15); }

// exp(i*pi*x*m) with fp64 angle reduction, scaled
__device__ inline f2 phasef(float xv, float m, float scale) {
    double ang = (double)xv * (double)m;
    double r = ang - 2.0 * rint(ang * 0.5);
    float sn, cs;
    sincospif((float)r, &sn, &cs);
    return (f2){cs * scale, sn * scale};
}

// ---------------------------------------------------------------------------
// k_outer (code unchanged — best-known config; (256,4) spills, R6)
// ---------------------------------------------------------------------------
__global__ __launch_bounds__(256, 2) void k_outer(const float* __restrict__ x,
                                                  const float* __restrict__ y,
                                                  float* __restrict__ pv,
                                                  float* __restrict__ pf,
                                                  int N, int cv, int cf)
{
    __shared__ f2 hs[PB][256];
    __shared__ float xs0[PB], xs1[PB], ys[PB];

    int bx = blockIdx.x;
    int t  = threadIdx.x;
    int ty = t >> 4, tx = t & 15;

    if (bx < cv) {
        int CP = (N + cv - 1) / cv;
        int n0 = bx * CP, n1 = min(N, n0 + CP);

        f2 acc[8][8];
        #pragma unroll
        for (int i = 0; i < 8; ++i)
            #pragma unroll
            for (int j = 0; j < 8; ++j) acc[i][j] = (f2){0.f, 0.f};

        for (int s = n0; s < n1; s += PB) {
            int cnt = min(PB, n1 - s);
            __syncthreads();
            if (t < cnt) {
                xs0[t] = x[2 * (s + t)];
                xs1[t] = x[2 * (s + t) + 1];
            }
            __syncthreads();
            for (int p = 0; p < cnt; ++p) {
                f2 g;
                if (t < 128)
                    g = (t == 127) ? (f2){0.f, 0.f} : phasef(xs0[p], (float)t - 63.f, 1.f);
                else {
                    int c = t - 128;
                    g = (c == 127) ? (f2){0.f, 0.f} : phasef(xs1[p], (float)c - 63.f, 1.f);
                }
                hs[p][t] = g;
            }
            __syncthreads();
            for (int p = 0; p < cnt; ++p) {
                f2 h1[8], h2[8], h2s[8];
                #pragma unroll
                for (int i = 0; i < 8; ++i) h1[i] = hs[p][ty * 8 + i];
                #pragma unroll
                for (int j = 0; j < 8; ++j) {
                    f2 b = hs[p][128 + tx + 16 * j];
                    h2[j] = b;
                    h2s[j] = (f2){-b.y, b.x};
                }
                #pragma unroll
                for (int i = 0; i < 8; ++i)
                    #pragma unroll
                    for (int j = 0; j < 8; ++j) {
                        acc[i][j] = acc[i][j] + f2s(h1[i].x) * h2[j];
                        acc[i][j] = acc[i][j] + f2s(h1[i].y) * h2s[j];
                    }
            }
        }
        __syncthreads();
        f2* out = (f2*)pv + (size_t)bx * 16384;
        #pragma unroll
        for (int i = 0; i < 8; ++i) {
            int a = ty * 8 + i;
            #pragma unroll
            for (int j = 0; j < 8; ++j)
                out[a * 128 + tx + 16 * j] = acc[i][j];
        }
    } else {
        int chunk = bx - cv;
        int CP = (N + cf - 1) / cf;
        int n0 = chunk * CP, n1 = min(N, n0 + CP);

        f2 acc[4][4];
        #pragma unroll
        for (int i = 0; i < 4; ++i)
            #pragma unroll
            for (int j = 0; j < 4; ++j) acc[i][j] = (f2){0.f, 0.f};

        for (int s = n0; s < n1; s += PB) {
            int cnt = min(PB, n1 - s);
            __syncthreads();
            if (t < cnt) {
                xs0[t] = x[2 * (s + t)];
                xs1[t] = x[2 * (s + t) + 1];
                ys[t]  = y[s + t];
            }
            __syncthreads();
            for (int p2 = 0; p2 < cnt; p2 += 2) {
                int p = p2 + (t >> 7);
                int c = t & 127;
                if (p < cnt) {
                    f2 g;
                    if (c < 64) g = phasef(xs0[p], (float)(32 - c), ys[p]);
                    else        g = phasef(xs1[p], (float)(32 - (c - 64)), 1.f);
                    hs[p][c] = g;
                }
            }
            __syncthreads();
            for (int p = 0; p < cnt; ++p) {
                f2 h1[4], h2[4], h2s[4];
                #pragma unroll
                for (int i = 0; i < 4; ++i) h1[i] = hs[p][ty * 4 + i];
                #pragma unroll
                for (int j = 0; j < 4; ++j) {
                    f2 b = hs[p][64 + tx + 16 * j];
                    h2[j] = b;
                    h2s[j] = (f2){-b.y, b.x};
                }
                #pragma unroll
                for (int i = 0; i < 4; ++i)
                    #pragma unroll
                    for (int j = 0; j < 4; ++j) {
                        acc[i][j] = acc[i][j] + f2s(h1[i].x) * h2[j];
                        acc[i][j] = acc[i][j] + f2s(h1[i].y) * h2s[j];
                    }
            }
        }
        __syncthreads();
        f2* out = (f2*)pf + (size_t)chunk * 4096;
        #pragma unroll
        for (int i = 0; i < 4; ++i) {
            int a = ty * 4 + i;
            #pragma unroll
            for (int j = 0; j < 4; ++j)
                out[a * 64 + tx + 16 * j] = acc[i][j];
        }
    }
}

// ---------------------------------------------------------------------------
// k_reduce (unchanged): partials -> circulant vcf (fp32) + rvec = ws*Fy (fp64)
// ---------------------------------------------------------------------------
__global__ __launch_bounds__(256) void k_reduce(const float* __restrict__ pv,
                                                const float* __restrict__ pf,
                                                const float* __restrict__ wsv,
                                                float* __restrict__ vcf,
                                                double2* __restrict__ rvec,
                                                int cv, int cf)
{
    int id = blockIdx.x * 256 + threadIdx.x;
    if (id < 131072) {
        int e = id >> 3, sl = id & 7;
        int q1 = e >> 7, q2 = e & 127;
        int a = (q1 + 63) & 127, b = (q2 + 63) & 127;
        int cn = cv >> 3;
        const float* src = pv + (size_t)(a * 128 + b) * 2
                              + (size_t)(sl * cn) * 32768;
        float sx = 0.f, sy = 0.f;
        for (int c = 0; c < cn; ++c) { sx += src[0]; sy += src[1]; src += 32768; }
        atomicAdd(&vcf[e * 2], sx);
        atomicAdd(&vcf[e * 2 + 1], sy);
    } else {
        int e = id - 131072;
        const float* s2p = pf + (size_t)e * 2;
        double fx = 0.0, fy2 = 0.0;
        for (int c = 0; c < cf; ++c) { fx += (double)s2p[0]; fy2 += (double)s2p[1]; s2p += 8192; }
        double w = (double)wsv[e];
        rvec[e] = make_double2(w * fx, w * fy2);
    }
}

// ---------------------------------------------------------------------------
// Twiddle constants: tw[t] = exp(-i*pi*t/64). bfly16 uses only t in
// {8s, 16q, 32q} — lane-uniform, compile-time. x*(1,0) and x*(0,-1) fold.
// ---------------------------------------------------------------------------
#define TC1 0.92387953251128676f   // cos(pi/8)
#define TS1 0.38268343236508977f   // sin(pi/8)
#define TSQ 0.70710678118654752f   // sqrt(2)/2

__device__ __constant__ const float C8x[8]  = {1.f, TC1, TSQ, TS1, 0.f, -TS1, -TSQ, -TC1};
__device__ __constant__ const float C8y[8]  = {0.f, -TS1, -TSQ, -TC1, -1.f, -TC1, -TSQ, -TS1};
__device__ __constant__ const float C16x[4] = {1.f, TSQ, 0.f, -TSQ};
__device__ __constant__ const float C16y[4] = {0.f, -TSQ, -1.f, -TSQ};

// ---------------------------------------------------------------------------
// Fused-stage FFT passes, STATIC register indexing only.
// Z[r*RS + cpad(c)], RS=137. tw[t] = exp(-i*pi*t/64) = W_128^t (setup only).
// ---------------------------------------------------------------------------
__device__ inline void bflyA_fwd(f2* L, const f2* tw, int b) {       // setup
    #pragma unroll
    for (int s = 0; s < 4; ++s) {                    // h=64
        f2 u0 = L[s], v0 = L[s + 4];
        L[s] = u0 + v0;
        L[s + 4] = cmulf(u0 - v0, tw[b + 16 * s]);
    }
    const int ss[4] = {0, 1, 4, 5};
    #pragma unroll
    for (int q = 0; q < 4; ++q) {                    // h=32
        int s = ss[q];
        f2 u0 = L[s], v0 = L[s + 2];
        L[s] = u0 + v0;
        L[s + 2] = cmulf(u0 - v0, tw[2 * b + 32 * (s & 1)]);
    }
    #pragma unroll
    for (int s = 0; s < 8; s += 2) {                 // h=16
        f2 u0 = L[s], v0 = L[s + 1];
        L[s] = u0 + v0;
        L[s + 1] = cmulf(u0 - v0, tw[4 * b]);
    }
}
// Register-twiddle variants: all CG-loop bflyA units share b = tid&15.
__device__ inline void bflyA_fwd_r(f2* L, const f2* t64, const f2* t32, f2 t16) {
    #pragma unroll
    for (int s = 0; s < 4; ++s) {                    // h=64
        f2 u0 = L[s], v0 = L[s + 4];
        L[s] = u0 + v0;
        L[s + 4] = cmulf(u0 - v0, t64[s]);
    }
    const int ss[4] = {0, 1, 4, 5};
    #pragma unroll
    for (int q = 0; q < 4; ++q) {                    // h=32
        int s = ss[q];
        f2 u0 = L[s], v0 = L[s + 2];
        L[s] = u0 + v0;
        L[s + 2] = cmulf(u0 - v0, t32[s & 1]);
    }
    #pragma unroll
    for (int s = 0; s < 8; s += 2) {                 // h=16
        f2 u0 = L[s], v0 = L[s + 1];
        L[s] = u0 + v0;
        L[s + 1] = cmulf(u0 - v0, t16);
    }
}
__device__ inline void bflyA_inv_r(f2* L, const f2* t64, const f2* t32, f2 t16) {
    #pragma unroll
    for (int s = 0; s < 8; s += 2) {                 // h=16
        f2 u0 = L[s];
        f2 vw = cmulcf(L[s + 1], t16);
        L[s] = u0 + vw; L[s + 1] = u0 - vw;
    }
    const int ss[4] = {0, 1, 4, 5};
    #pragma unroll
    for (int q = 0; q < 4; ++q) {                    // h=32
        int s = ss[q];
        f2 u0 = L[s];
        f2 vw = cmulcf(L[s + 2], t32[s & 1]);
        L[s] = u0 + vw; L[s + 2] = u0 - vw;
    }
    #pragma unroll
    for (int s = 0; s < 4; ++s) {                    // h=64
        f2 u0 = L[s];
        f2 vw = cmulcf(L[s + 4], t64[s]);
        L[s] = u0 + vw; L[s + 4] = u0 - vw;
    }
}
__device__ inline void bfly16_fwd(f2* M) {           // constant twiddles
    #pragma unroll
    for (int s = 0; s < 8; ++s) {                    // h=8
        f2 u0 = M[s], v0 = M[s + 8];
        M[s] = u0 + v0;
        M[s + 8] = cmulf(u0 - v0, (f2){C8x[s], C8y[s]});
    }
    #pragma unroll
    for (int q = 0; q < 8; ++q) {                    // h=4
        int s = (q & 3) + 8 * (q >> 2);
        f2 u0 = M[s], v0 = M[s + 4];
        M[s] = u0 + v0;
        M[s + 4] = cmulf(u0 - v0, (f2){C16x[s & 3], C16y[s & 3]});
    }
    #pragma unroll
    for (int q = 0; q < 8; ++q) {                    // h=2
        int s = (q & 1) + 4 * (q >> 1);
        f2 u0 = M[s], v0 = M[s + 2];
        M[s] = u0 + v0;
        f2 d = u0 - v0;
        M[s + 2] = (s & 1) ? (f2){d.y, -d.x} : d;    // * (0,-1) or * 1
    }
    #pragma unroll
    for (int s = 0; s < 16; s += 2) {                // h=1
        f2 u0 = M[s], v0 = M[s + 1];
        M[s] = u0 + v0; M[s + 1] = u0 - v0;
    }
}
__device__ inline void bfly16_inv(f2* M) {           // constant twiddles
    #pragma unroll
    for (int s = 0; s < 16; s += 2) {                // h=1
        f2 u0 = M[s], v0 = M[s + 1];
        M[s] = u0 + v0; M[s + 1] = u0 - v0;
    }
    #pragma unroll
    for (int q = 0; q < 8; ++q) {                    // h=2
        int s = (q & 1) + 4 * (q >> 1);
        f2 u0 = M[s];
        f2 v0 = M[s + 2];
        f2 vw = (s & 1) ? (f2){-v0.y, v0.x} : v0;    // conj(0,-1) = (0,1)
        M[s] = u0 + vw; M[s + 2] = u0 - vw;
    }
    #pragma unroll
    for (int q = 0; q < 8; ++q) {                    // h=4
        int s = (q & 3) + 8 * (q >> 2);
        f2 u0 = M[s];
        f2 vw = cmulcf(M[s + 4], (f2){C16x[s & 3], C16y[s & 3]});
        M[s] = u0 + vw; M[s + 4] = u0 - vw;
    }
    #pragma unroll
    for (int s = 0; s < 8; ++s) {                    // h=8
        f2 u0 = M[s];
        f2 vw = cmulcf(M[s + 8], (f2){C8x[s], C8y[s]});
        M[s] = u0 + vw; M[s + 8] = u0 - vw;
    }
}

__device__ inline void f_rowA(f2* Z, const f2* tw, int tid, int nrows, bool zup) {
    for (int u = tid; u < nrows * 16; u += 1024) {
        int r = u >> 4, b = u & 15;
        f2* row = Z + r * RS;
        f2 L[8];
        #pragma unroll
        for (int s = 0; s < 4; ++s) L[s] = row[17 * s + b];
        if (zup) {
            #pragma unroll
            for (int s = 4; s < 8; ++s) L[s] = (f2){0.f, 0.f};
        } else {
            #pragma unroll
            for (int s = 4; s < 8; ++s) L[s] = row[17 * s + b];
        }
        bflyA_fwd(L, tw, b);
        #pragma unroll
        for (int s = 0; s < 8; ++s) row[17 * s + b] = L[s];
    }
}
__device__ inline void f_rowB(f2* Z, int tid, int nrows) {
    for (int u = tid; u < nrows * 8; u += 1024) {
        int r = u >> 3, g = u & 7;
        f2* blk = Z + r * RS + g * 17;
        f2 M[16];
        #pragma unroll
        for (int s = 0; s < 16; ++s) M[s] = blk[s];
        bfly16_fwd(M);
        #pragma unroll
        for (int s = 0; s < 16; ++s) blk[s] = M[s];
    }
}
__device__ inline void i_rowB(f2* Z, int tid, int nrows) {
    for (int u = tid; u < nrows * 8; u += 1024) {
        int r = u >> 3, g = u & 7;
        f2* blk = Z + r * RS + g * 17;
        f2 M[16];
        #pragma unroll
        for (int s = 0; s < 16; ++s) M[s] = blk[s];
        bfly16_inv(M);
        #pragma unroll
        for (int s = 0; s < 16; ++s) blk[s] = M[s];
    }
}
__device__ inline void f_colA_setup(f2* Z, const f2* tw, int tid) {
    for (int u = tid; u < 2048; u += 1024) {
        int c = u >> 4, b = u & 15;
        int cp = cpad(c);
        f2 L[8];
        #pragma unroll
        for (int s = 0; s < 8; ++s) L[s] = Z[(b + 16 * s) * RS + cp];
        bflyA_fwd(L, tw, b);
        #pragma unroll
        for (int s = 0; s < 8; ++s) Z[(b + 16 * s) * RS + cp] = L[s];
    }
}
__device__ inline void f_colA_loop(f2* Z, int tid, const f2* t64, const f2* t32, f2 t16) {
    for (int u = tid; u < 2048; u += 1024) {
        int c = u >> 4, b = u & 15;         // b == tid&15 for both units
        int cp = cpad(c);
        f2 L[8];
        #pragma unroll
        for (int s = 0; s < 4; ++s) L[s] = Z[(b + 16 * s) * RS + cp];
        #pragma unroll
        for (int s = 4; s < 8; ++s) L[s] = (f2){0.f, 0.f};
        bflyA_fwd_r(L, t64, t32, t16);
        #pragma unroll
        for (int s = 0; s < 8; ++s) Z[(b + 16 * s) * RS + cp] = L[s];
    }
}
// i_colA: only rows<64 of the output are consumed downstream -> store s<4.
__device__ inline void i_colA_loop(f2* Z, int tid, const f2* t64, const f2* t32, f2 t16) {
    for (int u = tid; u < 2048; u += 1024) {
        int c = u >> 4, b = u & 15;
        int cp = cpad(c);
        f2 L[8];
        #pragma unroll
        for (int s = 0; s < 8; ++s) L[s] = Z[(b + 16 * s) * RS + cp];
        bflyA_inv_r(L, t64, t32, t16);
        #pragma unroll
        for (int s = 0; s < 4; ++s) Z[(b + 16 * s) * RS + cp] = L[s];
    }
}
// colB: lanes span 64 columns (c = tid&127) so banks vary across a wave.
__device__ inline void f_colB(f2* Z, int tid) {        // setup
    int c = tid & 127, g = tid >> 7;
    f2* col = Z + g * 16 * RS + cpad(c);
    f2 M[16];
    #pragma unroll
    for (int s = 0; s < 16; ++s) M[s] = col[s * RS];
    bfly16_fwd(M);
    #pragma unroll
    for (int s = 0; s < 16; ++s) col[s * RS] = M[s];
}
__device__ inline void it_colB(f2* Z, const f2* vfr, int tid) {
    int c = tid & 127, g = tid >> 7;
    f2* col = Z + g * 16 * RS + cpad(c);
    f2 M[16];
    #pragma unroll
    for (int s = 0; s < 16; ++s) M[s] = col[s * RS];
    bfly16_fwd(M);
    #pragma unroll
    for (int s = 0; s < 16; ++s) M[s] = cmulf(M[s], vfr[s]);
    bfly16_inv(M);
    #pragma unroll
    for (int s = 0; s < 16; ++s) col[s * RS] = M[s];
}

// One-barrier block reduce: >=1 barrier separates reuses of the same buffer.
__device__ inline double blk_reduce(double v, double* red, int wid, int m) {
    #pragma unroll
    for (int off = 32; off > 0; off >>= 1) v += __shfl_down(v, off);
    if (m == 0) red[wid] = v;
    __syncthreads();
    double s = 0.0;
    #pragma unroll
    for (int i = 0; i < 16; ++i) s += red[i];
    return s;
}

// ---------------------------------------------------------------------------
// k_cg_solve: R15 (see header). Thread tid owns elements
//   e_s = (tid>>4)*64 + (tid&15) + 16s  (row r=tid>>4, cols b+16s)
// ---------------------------------------------------------------------------
__global__ __launch_bounds__(1024)
__attribute__((amdgpu_waves_per_eu(4, 4)))
void k_cg_solve(
        const float* __restrict__ vcf, float* __restrict__ Vf,
        const double2* __restrict__ rvec, const float* __restrict__ wsv,
        const float* __restrict__ sig2, float* __restrict__ alg)
{
    __shared__ f2 Z[128 * RS];
    __shared__ f2 tw[64];
    __shared__ double redA[16], redB[16], redC[16];

    int tid = threadIdx.x;
    int wid = tid >> 6, m = tid & 63;
    int rr_ = tid >> 4, bb_ = tid & 15;          // this thread's rowA unit

    if (tid < 64) {
        float sn, cs;
        sincospif(-(float)tid / 64.f, &sn, &cs);
        tw[tid] = (f2){cs, sn};
    }
    __syncthreads();

    // ---- Vf setup (forward transform of vc, scrambled order)
    for (int i = tid; i < 16384; i += 1024)
        Z[(i >> 7) * RS + cpad(i & 127)] = ((const f2*)vcf)[i];
    __syncthreads();
    f_rowA(Z, tw, tid, 128, false); __syncthreads();
    f_rowB(Z, tid, 128);            __syncthreads();
    f_colA_setup(Z, tw, tid);       __syncthreads();
    f_colB(Z, tid);                 __syncthreads();
    for (int i = tid; i < 16384; i += 1024)
        ((f2*)Vf)[i] = Z[(i >> 7) * RS + cpad(i & 127)];
    __syncthreads();

    // ---- hoisted loop-invariants: bflyA twiddles (b = tid&15 for every
    //      CG-loop bflyA unit) and this thread's Vf slice.
    f2 tA64[4], tA32[2], tA16;
    #pragma unroll
    for (int s = 0; s < 4; ++s) tA64[s] = tw[bb_ + 16 * s];
    tA32[0] = tw[2 * bb_]; tA32[1] = tw[2 * bb_ + 32];
    tA16 = tw[4 * bb_];
    f2 vfr[16];
    {
        int c = tid & 127, g = tid >> 7;
        const f2* vf = (const f2*)Vf + g * 2048 + c;
        #pragma unroll
        for (int s = 0; s < 16; ++s) vfr[s] = vf[s * 128];
    }

    // ---- CG state (p, r, x all in regs; element e_s = rr_*64 + bb_ + 16s)
    double2 pR[4], rR[4], xR[4];
    float wsr[4];
    double rzp = 0.0;
    #pragma unroll
    for (int s = 0; s < 4; ++s) {
        int e = rr_ * 64 + bb_ + (s << 4);
        double2 bv = rvec[e];
        pR[s] = bv; rR[s] = bv;
        xR[s] = make_double2(0.0, 0.0);
        wsr[s] = wsv[e];
        rzp += bv.x * bv.x + bv.y * bv.y;
    }
    double rz = blk_reduce(rzp, redC, wid, m);
    double s2 = (double)sig2[0];
    const double inv16384 = 1.0 / 16384.0;
    __syncthreads();

    for (int it = 0; it < 50; ++it) {
        // ---- fused scatter + forward rowA: z = ws*p from regs (zero-padded)
        {
            f2* row = Z + rr_ * RS;
            f2 L[8];
            #pragma unroll
            for (int s = 0; s < 4; ++s)
                L[s] = (f2){(float)((double)wsr[s] * pR[s].x),
                            (float)((double)wsr[s] * pR[s].y)};
            #pragma unroll
            for (int s = 4; s < 8; ++s) L[s] = (f2){0.f, 0.f};
            bflyA_fwd_r(L, tA64, tA32, tA16);
            #pragma unroll
            for (int s = 0; s < 8; ++s) row[17 * s + bb_] = L[s];
        }
        __syncthreads();

        f_rowB(Z, tid, 64);                      __syncthreads();
        f_colA_loop(Z, tid, tA64, tA32, tA16);   __syncthreads();
        it_colB(Z, vfr, tid);                    __syncthreads();
        i_colA_loop(Z, tid, tA64, tA32, tA16);   __syncthreads();
        i_rowB(Z, tid, 64);                      __syncthreads();

        // ---- fused inverse rowA + Ap extraction (L[0..3] are our elements;
        //      unused upper-half outputs dead-code-eliminate)
        f2 az[4];
        {
            f2* row = Z + rr_ * RS;
            f2 L[8];
            #pragma unroll
            for (int s = 0; s < 8; ++s) L[s] = row[17 * s + bb_];
            bflyA_inv_r(L, tA64, tA32, tA16);
            #pragma unroll
            for (int s = 0; s < 4; ++s) az[s] = L[s];
        }
        double papp = 0.0;
        #pragma unroll
        for (int s = 0; s < 4; ++s) {
            double apx = (double)wsr[s] * (double)az[s].x * inv16384 + s2 * pR[s].x;
            double apy = (double)wsr[s] * (double)az[s].y * inv16384 + s2 * pR[s].y;
            papp += pR[s].x * apx + pR[s].y * apy;
        }
        double pap = blk_reduce(papp, redA, wid, m);
        double alpha = rz / (pap + 1e-30);

        double rrp = 0.0;
        #pragma unroll
        for (int s = 0; s < 4; ++s) {
            double apx = (double)wsr[s] * (double)az[s].x * inv16384 + s2 * pR[s].x;
            double apy = (double)wsr[s] * (double)az[s].y * inv16384 + s2 * pR[s].y;
            xR[s].x += alpha * pR[s].x; xR[s].y += alpha * pR[s].y;
            rR[s].x -= alpha * apx; rR[s].y -= alpha * apy;
            rrp += rR[s].x * rR[s].x + rR[s].y * rR[s].y;
        }
        double rzn = blk_reduce(rrp, redB, wid, m);
        double beta = rzn / (rz + 1e-30);
        rz = rzn;
        #pragma unroll
        for (int s = 0; s < 4; ++s) {
            pR[s].x = rR[s].x + beta * pR[s].x;
            pR[s].y = rR[s].y + beta * pR[s].y;
        }
    }

    // al = ws * x_50
    #pragma unroll
    for (int s = 0; s < 4; ++s) {
        int e = rr_ * 64 + bb_ + (s << 4);
        ((f2*)alg)[e] = (f2){(float)((double)wsr[s] * xR[s].x),
                             (float)((double)wsr[s] * xR[s].y)};
    }
}

// ---------------------------------------------------------------------------
// k_eval (unchanged)
// ---------------------------------------------------------------------------
__global__ __launch_bounds__(64) void k_eval(const float* __restrict__ xnew,
                                             const float* __restrict__ alg,
                                             float* __restrict__ out, int B)
{
    __shared__ float2 al[4096];
    int t = threadIdx.x;
    int b = blockIdx.x * 64 + t;
    for (int i = t; i < 4096; i += 64) {
        f2 v = ((const f2*)alg)[i];
        al[i] = make_float2(v.x, v.y);
    }
    float x0 = 0.f, x1 = 0.f;
    if (b < B) { x0 = xnew[2 * b]; x1 = xnew[2 * b + 1]; }
    __syncthreads();
    double2 wstep; { double sn, cs; sincospi((double)x1, &sn, &cs); wstep = make_double2(cs, sn); }
    double mu = 0.0;
    for (int jg = 0; jg < 4; ++jg) {
        float2 tacc[16];
        for (int q = 0; q < 16; ++q) tacc[q] = make_float2(0.f, 0.f);
        double2 e2; { double sn, cs; sincospi(-32.0 * (double)x1, &sn, &cs); e2 = make_double2(cs, sn); }
        for (int k = 0; k < 64; ++k) {
            float2 e2f = make_float2((float)e2.x, (float)e2.y);
            for (int q = 0; q < 16; ++q) {
                int j = jg * 16 + q;
                float2 a = al[j * 64 + k];
                tacc[q].x += a.x * e2f.x - a.y * e2f.y;
                tacc[q].y += a.x * e2f.y + a.y * e2f.x;
            }
            e2 = make_double2(e2.x * wstep.x - e2.y * wstep.y,
                              e2.x * wstep.y + e2.y * wstep.x);
        }
        for (int q = 0; q < 16; ++q) {
            int j = jg * 16 + q;
            double sn, cs;
            sincospi((double)x0 * (double)(j - 32), &sn, &cs);
            mu += cs * (double)tacc[q].x - sn * (double)tacc[q].y;
        }
    }
    if (b < B) out[b] = (float)mu;
}

// ---------------------------------------------------------------------------

extern "C" void kernel_launch(void* const* d_in, const int* in_sizes, int n_in,
                              void* d_out, int out_size, void* d_ws, size_t ws_size,
                              hipStream_t stream)
{
    const float* x    = (const float*)d_in[0];
    const float* y    = (const float*)d_in[1];
    const float* xnew = (const float*)d_in[2];
    const float* wsv  = (const float*)d_in[3];
    const float* sig2 = (const float*)d_in[4];
    int N = in_sizes[1];
    int B = in_sizes[2] / 2;

    char* base = (char*)d_ws;
    size_t o = 0;
    float*   vcf  = (float*)(base + o);   o += 131072;   // 128x128 circulant vc (fp32)
    float*   Vf   = (float*)(base + o);   o += 131072;   // scrambled 2D FFT of vc
    double2* rvec = (double2*)(base + o); o += 65536;    // b = ws*Fy (fp64)
    float*   alg  = (float*)(base + o);   o += 32768;    // ws*x_50 (fp32 complex)
    size_t avail = (ws_size > o) ? ws_size - o : 0;
    int cv = (int)(avail / 139264);                      // 128KB v + 8KB fy per unit
    if (cv > 768) cv = 768;                              // R13: raised 384->768
    if (cv < 16) cv = 16;                                //   (grid was the
    cv &= ~15;                                           //    occupancy binder)
    int cf = cv / 4;
    float* pv = (float*)(base + o); o += (size_t)cv * 131072;
    float* pf = (float*)(base + o);

    hipMemsetAsync(vcf, 0, 131072, stream);              // fp32 atomic target

    k_outer<<<cv + cf, 256, 0, stream>>>(x, y, pv, pf, N, cv, cf);
    k_reduce<<<528, 256, 0, stream>>>(pv, pf, wsv, vcf, rvec, cv, cf);
    k_cg_solve<<<1, 1024, 0, stream>>>(vcf, Vf, rvec, wsv, sig2, alg);
    k_eval<<<(B + 63) / 64, 64, 0, stream>>>(xnew, alg, (float*)d_out, B);
}

// Round 3
// 1275.206 us; speedup vs baseline: 1.1477x; 1.1477x over previous
//
#include <hip/hip_runtime.h>
#include <math.h>

// ---------------------------------------------------------------------------
// GP posterior mean:
//   k_outer : separable NUFFT outer products, fp32 atomic-free partials.
//   k_reduce: partials -> fp32 circulant table vcf + fp64 rhs b.
//   k_cg_solve: R16 = R14 base (918us verified) + only the zero-register-cost
//     parts of R15:
//       - bfly16 twiddles as LOCAL const tables -> SROA-folded immediates
//         (kills ~43k lane-uniform LDS reads/iter). No __constant__ mem.
//       - i_colA stores only rows<64 (only corner consumed downstream).
//     R15 lesson: VGPR budget is pinned at 64 (attribute didn't raise it);
//     CG state already fills it. Hoisting vfr[16]/tA[7] => scratch spills
//     (FETCH +66KB, WRITE +136KB, dur +90us). DO NOT hoist into registers;
//     bflyA twiddles stay in LDS tw[], Vf reads stay L2.
//     R14: CG-state remap (thread owns row tid>>4, cols (tid&15)+16s);
//     fused scatter+rowA and i_rowA+Ap; x in regs. 8 barriers/iter.
//     R12 lesson kept: scalar cmul + 2 separate reduces.
//   k_eval  : posterior mean at test points from al = ws*x_50.
// ---------------------------------------------------------------------------

typedef float f2 __attribute__((ext_vector_type(2)));
#define PB 16
#define RS 137          // Z row stride in f2 (8 blocks x 17)

__device__ inline f2 f2s(float s) { return (f2){s, s}; }
__device__ inline f2 cmulf(f2 a, f2 b) {   // a*b
    return (f2){a.x * b.x - a.y * b.y, a.x * b.y + a.y * b.x};
}
__device__ inline f2 cmulcf(f2 a, f2 b) {  // a*conj(b)
    return (f2){a.x * b.x + a.y * b.y, a.y * b.x - a.x * b.y};
}
__device__ inline int cpad(int c) { return (c >> 4) * 17 + (c & 15); }

// exp(i*pi*x*m) with fp64 angle reduction, scaled
__device__ inline f2 phasef(float xv, float m, float scale) {
    double ang = (double)xv * (double)m;
    double r = ang - 2.0 * rint(ang * 0.5);
    float sn, cs;
    sincospif((float)r, &sn, &cs);
    return (f2){cs * scale, sn * scale};
}

// ---------------------------------------------------------------------------
// k_outer (code unchanged — best-known config; (256,4) spills, R6)
// ---------------------------------------------------------------------------
__global__ __launch_bounds__(256, 2) void k_outer(const float* __restrict__ x,
                                                  const float* __restrict__ y,
                                                  float* __restrict__ pv,
                                                  float* __restrict__ pf,
                                                  int N, int cv, int cf)
{
    __shared__ f2 hs[PB][256];
    __shared__ float xs0[PB], xs1[PB], ys[PB];

    int bx = blockIdx.x;
    int t  = threadIdx.x;
    int ty = t >> 4, tx = t & 15;

    if (bx < cv) {
        int CP = (N + cv - 1) / cv;
        int n0 = bx * CP, n1 = min(N, n0 + CP);

        f2 acc[8][8];
        #pragma unroll
        for (int i = 0; i < 8; ++i)
            #pragma unroll
            for (int j = 0; j < 8; ++j) acc[i][j] = (f2){0.f, 0.f};

        for (int s = n0; s < n1; s += PB) {
            int cnt = min(PB, n1 - s);
            __syncthreads();
            if (t < cnt) {
                xs0[t] = x[2 * (s + t)];
                xs1[t] = x[2 * (s + t) + 1];
            }
            __syncthreads();
            for (int p = 0; p < cnt; ++p) {
                f2 g;
                if (t < 128)
                    g = (t == 127) ? (f2){0.f, 0.f} : phasef(xs0[p], (float)t - 63.f, 1.f);
                else {
                    int c = t - 128;
                    g = (c == 127) ? (f2){0.f, 0.f} : phasef(xs1[p], (float)c - 63.f, 1.f);
                }
                hs[p][t] = g;
            }
            __syncthreads();
            for (int p = 0; p < cnt; ++p) {
                f2 h1[8], h2[8], h2s[8];
                #pragma unroll
                for (int i = 0; i < 8; ++i) h1[i] = hs[p][ty * 8 + i];
                #pragma unroll
                for (int j = 0; j < 8; ++j) {
                    f2 b = hs[p][128 + tx + 16 * j];
                    h2[j] = b;
                    h2s[j] = (f2){-b.y, b.x};
                }
                #pragma unroll
                for (int i = 0; i < 8; ++i)
                    #pragma unroll
                    for (int j = 0; j < 8; ++j) {
                        acc[i][j] = acc[i][j] + f2s(h1[i].x) * h2[j];
                        acc[i][j] = acc[i][j] + f2s(h1[i].y) * h2s[j];
                    }
            }
        }
        __syncthreads();
        f2* out = (f2*)pv + (size_t)bx * 16384;
        #pragma unroll
        for (int i = 0; i < 8; ++i) {
            int a = ty * 8 + i;
            #pragma unroll
            for (int j = 0; j < 8; ++j)
                out[a * 128 + tx + 16 * j] = acc[i][j];
        }
    } else {
        int chunk = bx - cv;
        int CP = (N + cf - 1) / cf;
        int n0 = chunk * CP, n1 = min(N, n0 + CP);

        f2 acc[4][4];
        #pragma unroll
        for (int i = 0; i < 4; ++i)
            #pragma unroll
            for (int j = 0; j < 4; ++j) acc[i][j] = (f2){0.f, 0.f};

        for (int s = n0; s < n1; s += PB) {
            int cnt = min(PB, n1 - s);
            __syncthreads();
            if (t < cnt) {
                xs0[t] = x[2 * (s + t)];
                xs1[t] = x[2 * (s + t) + 1];
                ys[t]  = y[s + t];
            }
            __syncthreads();
            for (int p2 = 0; p2 < cnt; p2 += 2) {
                int p = p2 + (t >> 7);
                int c = t & 127;
                if (p < cnt) {
                    f2 g;
                    if (c < 64) g = phasef(xs0[p], (float)(32 - c), ys[p]);
                    else        g = phasef(xs1[p], (float)(32 - (c - 64)), 1.f);
                    hs[p][c] = g;
                }
            }
            __syncthreads();
            for (int p = 0; p < cnt; ++p) {
                f2 h1[4], h2[4], h2s[4];
                #pragma unroll
                for (int i = 0; i < 4; ++i) h1[i] = hs[p][ty * 4 + i];
                #pragma unroll
                for (int j = 0; j < 4; ++j) {
                    f2 b = hs[p][64 + tx + 16 * j];
                    h2[j] = b;
                    h2s[j] = (f2){-b.y, b.x};
                }
                #pragma unroll
                for (int i = 0; i < 4; ++i)
                    #pragma unroll
                    for (int j = 0; j < 4; ++j) {
                        acc[i][j] = acc[i][j] + f2s(h1[i].x) * h2[j];
                        acc[i][j] = acc[i][j] + f2s(h1[i].y) * h2s[j];
                    }
            }
        }
        __syncthreads();
        f2* out = (f2*)pf + (size_t)chunk * 4096;
        #pragma unroll
        for (int i = 0; i < 4; ++i) {
            int a = ty * 4 + i;
            #pragma unroll
            for (int j = 0; j < 4; ++j)
                out[a * 64 + tx + 16 * j] = acc[i][j];
        }
    }
}

// ---------------------------------------------------------------------------
// k_reduce (unchanged): partials -> circulant vcf (fp32) + rvec = ws*Fy (fp64)
// ---------------------------------------------------------------------------
__global__ __launch_bounds__(256) void k_reduce(const float* __restrict__ pv,
                                                const float* __restrict__ pf,
                                                const float* __restrict__ wsv,
                                                float* __restrict__ vcf,
                                                double2* __restrict__ rvec,
                                                int cv, int cf)
{
    int id = blockIdx.x * 256 + threadIdx.x;
    if (id < 131072) {
        int e = id >> 3, sl = id & 7;
        int q1 = e >> 7, q2 = e & 127;
        int a = (q1 + 63) & 127, b = (q2 + 63) & 127;
        int cn = cv >> 3;
        const float* src = pv + (size_t)(a * 128 + b) * 2
                              + (size_t)(sl * cn) * 32768;
        float sx = 0.f, sy = 0.f;
        for (int c = 0; c < cn; ++c) { sx += src[0]; sy += src[1]; src += 32768; }
        atomicAdd(&vcf[e * 2], sx);
        atomicAdd(&vcf[e * 2 + 1], sy);
    } else {
        int e = id - 131072;
        const float* s2p = pf + (size_t)e * 2;
        double fx = 0.0, fy2 = 0.0;
        for (int c = 0; c < cf; ++c) { fx += (double)s2p[0]; fy2 += (double)s2p[1]; s2p += 8192; }
        double w = (double)wsv[e];
        rvec[e] = make_double2(w * fx, w * fy2);
    }
}

// ---------------------------------------------------------------------------
// Fused-stage FFT passes, STATIC register indexing only.
// Z[r*RS + cpad(c)], RS=137. tw[t] = exp(-i*pi*t/64) = W_128^t.
// bfly16 twiddles are lane-uniform -> LOCAL const tables (SROA-folded to
// immediates after unroll; no LDS / no constant-mem traffic).
// ---------------------------------------------------------------------------
#define TC1 0.92387953251128676f   // cos(pi/8)
#define TS1 0.38268343236508977f   // sin(pi/8)
#define TSQ 0.70710678118654752f   // sqrt(2)/2

__device__ inline void bflyA_fwd(f2* L, const f2* tw, int b) {
    #pragma unroll
    for (int s = 0; s < 4; ++s) {                    // h=64
        f2 u0 = L[s], v0 = L[s + 4];
        L[s] = u0 + v0;
        L[s + 4] = cmulf(u0 - v0, tw[b + 16 * s]);
    }
    const int ss[4] = {0, 1, 4, 5};
    #pragma unroll
    for (int q = 0; q < 4; ++q) {                    // h=32
        int s = ss[q];
        f2 u0 = L[s], v0 = L[s + 2];
        L[s] = u0 + v0;
        L[s + 2] = cmulf(u0 - v0, tw[2 * b + 32 * (s & 1)]);
    }
    #pragma unroll
    for (int s = 0; s < 8; s += 2) {                 // h=16
        f2 u0 = L[s], v0 = L[s + 1];
        L[s] = u0 + v0;
        L[s + 1] = cmulf(u0 - v0, tw[4 * b]);
    }
}
__device__ inline void bflyA_inv(f2* L, const f2* tw, int b) {
    #pragma unroll
    for (int s = 0; s < 8; s += 2) {                 // h=16
        f2 u0 = L[s];
        f2 vw = cmulcf(L[s + 1], tw[4 * b]);
        L[s] = u0 + vw; L[s + 1] = u0 - vw;
    }
    const int ss[4] = {0, 1, 4, 5};
    #pragma unroll
    for (int q = 0; q < 4; ++q) {                    // h=32
        int s = ss[q];
        f2 u0 = L[s];
        f2 vw = cmulcf(L[s + 2], tw[2 * b + 32 * (s & 1)]);
        L[s] = u0 + vw; L[s + 2] = u0 - vw;
    }
    #pragma unroll
    for (int s = 0; s < 4; ++s) {                    // h=64
        f2 u0 = L[s];
        f2 vw = cmulcf(L[s + 4], tw[b + 16 * s]);
        L[s] = u0 + vw; L[s + 4] = u0 - vw;
    }
}
__device__ inline void bfly16_fwd(f2* M) {
    const float c8x[8]  = {1.f, TC1, TSQ, TS1, 0.f, -TS1, -TSQ, -TC1};
    const float c8y[8]  = {0.f, -TS1, -TSQ, -TC1, -1.f, -TC1, -TSQ, -TS1};
    const float c16x[4] = {1.f, TSQ, 0.f, -TSQ};
    const float c16y[4] = {0.f, -TSQ, -1.f, -TSQ};
    #pragma unroll
    for (int s = 0; s < 8; ++s) {                    // h=8
        f2 u0 = M[s], v0 = M[s + 8];
        M[s] = u0 + v0;
        M[s + 8] = cmulf(u0 - v0, (f2){c8x[s], c8y[s]});
    }
    #pragma unroll
    for (int q = 0; q < 8; ++q) {                    // h=4
        int s = (q & 3) + 8 * (q >> 2);
        f2 u0 = M[s], v0 = M[s + 4];
        M[s] = u0 + v0;
        M[s + 4] = cmulf(u0 - v0, (f2){c16x[s & 3], c16y[s & 3]});
    }
    #pragma unroll
    for (int q = 0; q < 8; ++q) {                    // h=2
        int s = (q & 1) + 4 * (q >> 1);
        f2 u0 = M[s], v0 = M[s + 2];
        M[s] = u0 + v0;
        f2 d = u0 - v0;
        M[s + 2] = (s & 1) ? (f2){d.y, -d.x} : d;    // * (0,-1) or * 1
    }
    #pragma unroll
    for (int s = 0; s < 16; s += 2) {                // h=1
        f2 u0 = M[s], v0 = M[s + 1];
        M[s] = u0 + v0; M[s + 1] = u0 - v0;
    }
}
__device__ inline void bfly16_inv(f2* M) {
    const float c8x[8]  = {1.f, TC1, TSQ, TS1, 0.f, -TS1, -TSQ, -TC1};
    const float c8y[8]  = {0.f, -TS1, -TSQ, -TC1, -1.f, -TC1, -TSQ, -TS1};
    const float c16x[4] = {1.f, TSQ, 0.f, -TSQ};
    const float c16y[4] = {0.f, -TSQ, -1.f, -TSQ};
    #pragma unroll
    for (int s = 0; s < 16; s += 2) {                // h=1
        f2 u0 = M[s], v0 = M[s + 1];
        M[s] = u0 + v0; M[s + 1] = u0 - v0;
    }
    #pragma unroll
    for (int q = 0; q < 8; ++q) {                    // h=2
        int s = (q & 1) + 4 * (q >> 1);
        f2 u0 = M[s];
        f2 v0 = M[s + 2];
        f2 vw = (s & 1) ? (f2){-v0.y, v0.x} : v0;    // conj(0,-1) = (0,1)
        M[s] = u0 + vw; M[s + 2] = u0 - vw;
    }
    #pragma unroll
    for (int q = 0; q < 8; ++q) {                    // h=4
        int s = (q & 3) + 8 * (q >> 2);
        f2 u0 = M[s];
        f2 vw = cmulcf(M[s + 4], (f2){c16x[s & 3], c16y[s & 3]});
        M[s] = u0 + vw; M[s + 4] = u0 - vw;
    }
    #pragma unroll
    for (int s = 0; s < 8; ++s) {                    // h=8
        f2 u0 = M[s];
        f2 vw = cmulcf(M[s + 8], (f2){c8x[s], c8y[s]});
        M[s] = u0 + vw; M[s + 8] = u0 - vw;
    }
}

__device__ inline void f_rowA(f2* Z, const f2* tw, int tid, int nrows, bool zup) {
    for (int u = tid; u < nrows * 16; u += 1024) {
        int r = u >> 4, b = u & 15;
        f2* row = Z + r * RS;
        f2 L[8];
        #pragma unroll
        for (int s = 0; s < 4; ++s) L[s] = row[17 * s + b];
        if (zup) {
            #pragma unroll
            for (int s = 4; s < 8; ++s) L[s] = (f2){0.f, 0.f};
        } else {
            #pragma unroll
            for (int s = 4; s < 8; ++s) L[s] = row[17 * s + b];
        }
        bflyA_fwd(L, tw, b);
        #pragma unroll
        for (int s = 0; s < 8; ++s) row[17 * s + b] = L[s];
    }
}
__device__ inline void f_rowB(f2* Z, int tid, int nrows) {
    for (int u = tid; u < nrows * 8; u += 1024) {
        int r = u >> 3, g = u & 7;
        f2* blk = Z + r * RS + g * 17;
        f2 M[16];
        #pragma unroll
        for (int s = 0; s < 16; ++s) M[s] = blk[s];
        bfly16_fwd(M);
        #pragma unroll
        for (int s = 0; s < 16; ++s) blk[s] = M[s];
    }
}
__device__ inline void i_rowB(f2* Z, int tid, int nrows) {
    for (int u = tid; u < nrows * 8; u += 1024) {
        int r = u >> 3, g = u & 7;
        f2* blk = Z + r * RS + g * 17;
        f2 M[16];
        #pragma unroll
        for (int s = 0; s < 16; ++s) M[s] = blk[s];
        bfly16_inv(M);
        #pragma unroll
        for (int s = 0; s < 16; ++s) blk[s] = M[s];
    }
}
__device__ inline void f_colA(f2* Z, const f2* tw, int tid, bool zup) {
    for (int u = tid; u < 2048; u += 1024) {
        int c = u >> 4, b = u & 15;
        int cp = cpad(c);
        f2 L[8];
        #pragma unroll
        for (int s = 0; s < 4; ++s) L[s] = Z[(b + 16 * s) * RS + cp];
        if (zup) {
            #pragma unroll
            for (int s = 4; s < 8; ++s) L[s] = (f2){0.f, 0.f};
        } else {
            #pragma unroll
            for (int s = 4; s < 8; ++s) L[s] = Z[(b + 16 * s) * RS + cp];
        }
        bflyA_fwd(L, tw, b);
        #pragma unroll
        for (int s = 0; s < 8; ++s) Z[(b + 16 * s) * RS + cp] = L[s];
    }
}
// i_colA: only rows<64 of the output are consumed downstream -> store s<4.
__device__ inline void i_colA(f2* Z, const f2* tw, int tid) {
    for (int u = tid; u < 2048; u += 1024) {
        int c = u >> 4, b = u & 15;
        int cp = cpad(c);
        f2 L[8];
        #pragma unroll
        for (int s = 0; s < 8; ++s) L[s] = Z[(b + 16 * s) * RS + cp];
        bflyA_inv(L, tw, b);
        #pragma unroll
        for (int s = 0; s < 4; ++s) Z[(b + 16 * s) * RS + cp] = L[s];
    }
}
// colB: lanes span 64 columns (c = tid&127) so banks vary across a wave.
__device__ inline void f_colB(f2* Z, int tid) {        // setup
    int c = tid & 127, g = tid >> 7;
    f2* col = Z + g * 16 * RS + cpad(c);
    f2 M[16];
    #pragma unroll
    for (int s = 0; s < 16; ++s) M[s] = col[s * RS];
    bfly16_fwd(M);
    #pragma unroll
    for (int s = 0; s < 16; ++s) col[s * RS] = M[s];
}
__device__ inline void it_colB(f2* Z, const f2* Vfg, int tid) {
    int c = tid & 127, g = tid >> 7;
    f2* col = Z + g * 16 * RS + cpad(c);
    const f2* vf = Vfg + g * 16 * 128 + c;
    f2 M[16];
    #pragma unroll
    for (int s = 0; s < 16; ++s) M[s] = col[s * RS];
    bfly16_fwd(M);
    #pragma unroll
    for (int s = 0; s < 16; ++s) M[s] = cmulf(M[s], vf[s * 128]);
    bfly16_inv(M);
    #pragma unroll
    for (int s = 0; s < 16; ++s) col[s * RS] = M[s];
}

// One-barrier block reduce: >=1 barrier separates reuses of the same buffer.
__device__ inline double blk_reduce(double v, double* red, int wid, int m) {
    #pragma unroll
    for (int off = 32; off > 0; off >>= 1) v += __shfl_down(v, off);
    if (m == 0) red[wid] = v;
    __syncthreads();
    double s = 0.0;
    #pragma unroll
    for (int i = 0; i < 16; ++i) s += red[i];
    return s;
}

// ---------------------------------------------------------------------------
// k_cg_solve: R16 (see header). Thread tid owns elements
//   e_s = (tid>>4)*64 + (tid&15) + 16s  (row r=tid>>4, cols b+16s)
// ---------------------------------------------------------------------------
__global__ __launch_bounds__(1024, 4) void k_cg_solve(
        const float* __restrict__ vcf, float* __restrict__ Vf,
        const double2* __restrict__ rvec, const float* __restrict__ wsv,
        const float* __restrict__ sig2, float* __restrict__ alg)
{
    __shared__ f2 Z[128 * RS];
    __shared__ f2 tw[64];
    __shared__ double redA[16], redB[16], redC[16];

    int tid = threadIdx.x;
    int wid = tid >> 6, m = tid & 63;
    int rr_ = tid >> 4, bb_ = tid & 15;          // this thread's rowA unit

    if (tid < 64) {
        float sn, cs;
        sincospif(-(float)tid / 64.f, &sn, &cs);
        tw[tid] = (f2){cs, sn};
    }
    __syncthreads();

    // ---- Vf setup (forward transform of vc, scrambled order)
    for (int i = tid; i < 16384; i += 1024)
        Z[(i >> 7) * RS + cpad(i & 127)] = ((const f2*)vcf)[i];
    __syncthreads();
    f_rowA(Z, tw, tid, 128, false); __syncthreads();
    f_rowB(Z, tid, 128);            __syncthreads();
    f_colA(Z, tw, tid, false);      __syncthreads();
    f_colB(Z, tid);                 __syncthreads();
    for (int i = tid; i < 16384; i += 1024)
        ((f2*)Vf)[i] = Z[(i >> 7) * RS + cpad(i & 127)];
    __syncthreads();

    // ---- CG state (p, r, x all in regs; element e_s = rr_*64 + bb_ + 16s)
    double2 pR[4], rR[4], xR[4];
    float wsr[4];
    double rzp = 0.0;
    #pragma unroll
    for (int s = 0; s < 4; ++s) {
        int e = rr_ * 64 + bb_ + (s << 4);
        double2 bv = rvec[e];
        pR[s] = bv; rR[s] = bv;
        xR[s] = make_double2(0.0, 0.0);
        wsr[s] = wsv[e];
        rzp += bv.x * bv.x + bv.y * bv.y;
    }
    double rz = blk_reduce(rzp, redC, wid, m);
    double s2 = (double)sig2[0];
    const double inv16384 = 1.0 / 16384.0;
    __syncthreads();

    for (int it = 0; it < 50; ++it) {
        // ---- fused scatter + forward rowA: z = ws*p from regs (zero-padded)
        {
            f2* row = Z + rr_ * RS;
            f2 L[8];
            #pragma unroll
            for (int s = 0; s < 4; ++s)
                L[s] = (f2){(float)((double)wsr[s] * pR[s].x),
                            (float)((double)wsr[s] * pR[s].y)};
            #pragma unroll
            for (int s = 4; s < 8; ++s) L[s] = (f2){0.f, 0.f};
            bflyA_fwd(L, tw, bb_);
            #pragma unroll
            for (int s = 0; s < 8; ++s) row[17 * s + bb_] = L[s];
        }
        __syncthreads();

        f_rowB(Z, tid, 64);                      __syncthreads();
        f_colA(Z, tw, tid, true);                __syncthreads();
        it_colB(Z, (const f2*)Vf, tid);          __syncthreads();
        i_colA(Z, tw, tid);                      __syncthreads();
        i_rowB(Z, tid, 64);                      __syncthreads();

        // ---- fused inverse rowA + Ap extraction (L[0..3] are our elements;
        //      unused upper-half outputs dead-code-eliminate)
        f2 az[4];
        {
            f2* row = Z + rr_ * RS;
            f2 L[8];
            #pragma unroll
            for (int s = 0; s < 8; ++s) L[s] = row[17 * s + bb_];
            bflyA_inv(L, tw, bb_);
            #pragma unroll
            for (int s = 0; s < 4; ++s) az[s] = L[s];
        }
        double papp = 0.0;
        #pragma unroll
        for (int s = 0; s < 4; ++s) {
            double apx = (double)wsr[s] * (double)az[s].x * inv16384 + s2 * pR[s].x;
            double apy = (double)wsr[s] * (double)az[s].y * inv16384 + s2 * pR[s].y;
            papp += pR[s].x * apx + pR[s].y * apy;
        }
        double pap = blk_reduce(papp, redA, wid, m);
        double alpha = rz / (pap + 1e-30);

        double rrp = 0.0;
        #pragma unroll
        for (int s = 0; s < 4; ++s) {
            double apx = (double)wsr[s] * (double)az[s].x * inv16384 + s2 * pR[s].x;
            double apy = (double)wsr[s] * (double)az[s].y * inv16384 + s2 * pR[s].y;
            xR[s].x += alpha * pR[s].x; xR[s].y += alpha * pR[s].y;
            rR[s].x -= alpha * apx; rR[s].y -= alpha * apy;
            rrp += rR[s].x * rR[s].x + rR[s].y * rR[s].y;
        }
        double rzn = blk_reduce(rrp, redB, wid, m);
        double beta = rzn / (rz + 1e-30);
        rz = rzn;
        #pragma unroll
        for (int s = 0; s < 4; ++s) {
            pR[s].x = rR[s].x + beta * pR[s].x;
            pR[s].y = rR[s].y + beta * pR[s].y;
        }
    }

    // al = ws * x_50
    #pragma unroll
    for (int s = 0; s < 4; ++s) {
        int e = rr_ * 64 + bb_ + (s << 4);
        ((f2*)alg)[e] = (f2){(float)((double)wsr[s] * xR[s].x),
                             (float)((double)wsr[s] * xR[s].y)};
    }
}

// ---------------------------------------------------------------------------
// k_eval (unchanged)
// ---------------------------------------------------------------------------
__global__ __launch_bounds__(64) void k_eval(const float* __restrict__ xnew,
                                             const float* __restrict__ alg,
                                             float* __restrict__ out, int B)
{
    __shared__ float2 al[4096];
    int t = threadIdx.x;
    int b = blockIdx.x * 64 + t;
    for (int i = t; i < 4096; i += 64) {
        f2 v = ((const f2*)alg)[i];
        al[i] = make_float2(v.x, v.y);
    }
    float x0 = 0.f, x1 = 0.f;
    if (b < B) { x0 = xnew[2 * b]; x1 = xnew[2 * b + 1]; }
    __syncthreads();
    double2 wstep; { double sn, cs; sincospi((double)x1, &sn, &cs); wstep = make_double2(cs, sn); }
    double mu = 0.0;
    for (int jg = 0; jg < 4; ++jg) {
        float2 tacc[16];
        for (int q = 0; q < 16; ++q) tacc[q] = make_float2(0.f, 0.f);
        double2 e2; { double sn, cs; sincospi(-32.0 * (double)x1, &sn, &cs); e2 = make_double2(cs, sn); }
        for (int k = 0; k < 64; ++k) {
            float2 e2f = make_float2((float)e2.x, (float)e2.y);
            for (int q = 0; q < 16; ++q) {
                int j = jg * 16 + q;
                float2 a = al[j * 64 + k];
                tacc[q].x += a.x * e2f.x - a.y * e2f.y;
                tacc[q].y += a.x * e2f.y + a.y * e2f.x;
            }
            e2 = make_double2(e2.x * wstep.x - e2.y * wstep.y,
                              e2.x * wstep.y + e2.y * wstep.x);
        }
        for (int q = 0; q < 16; ++q) {
            int j = jg * 16 + q;
            double sn, cs;
            sincospi((double)x0 * (double)(j - 32), &sn, &cs);
            mu += cs * (double)tacc[q].x - sn * (double)tacc[q].y;
        }
    }
    if (b < B) out[b] = (float)mu;
}

// ---------------------------------------------------------------------------

extern "C" void kernel_launch(void* const* d_in, const int* in_sizes, int n_in,
                              void* d_out, int out_size, void* d_ws, size_t ws_size,
                              hipStream_t stream)
{
    const float* x    = (const float*)d_in[0];
    const float* y    = (const float*)d_in[1];
    const float* xnew = (const float*)d_in[2];
    const float* wsv  = (const float*)d_in[3];
    const float* sig2 = (const float*)d_in[4];
    int N = in_sizes[1];
    int B = in_sizes[2] / 2;

    char* base = (char*)d_ws;
    size_t o = 0;
    float*   vcf  = (float*)(base + o);   o += 131072;   // 128x128 circulant vc (fp32)
    float*   Vf   = (float*)(base + o);   o += 131072;   // scrambled 2D FFT of vc
    double2* rvec = (double2*)(base + o); o += 65536;    // b = ws*Fy (fp64)
    float*   alg  = (float*)(base + o);   o += 32768;    // ws*x_50 (fp32 complex)
    size_t avail = (ws_size > o) ? ws_size - o : 0;
    int cv = (int)(avail / 139264);                      // 128KB v + 8KB fy per unit
    if (cv > 768) cv = 768;                              // R13: raised 384->768
    if (cv < 16) cv = 16;                                //   (grid was the
    cv &= ~15;                                           //    occupancy binder)
    int cf = cv / 4;
    float* pv = (float*)(base + o); o += (size_t)cv * 131072;
    float* pf = (float*)(base + o);

    hipMemsetAsync(vcf, 0, 131072, stream);              // fp32 atomic target

    k_outer<<<cv + cf, 256, 0, stream>>>(x, y, pv, pf, N, cv, cf);
    k_reduce<<<528, 256, 0, stream>>>(pv, pf, wsv, vcf, rvec, cv, cf);
    k_cg_solve<<<1, 1024, 0, stream>>>(vcf, Vf, rvec, wsv, sig2, alg);
    k_eval<<<(B + 63) / 64, 64, 0, stream>>>(xnew, alg, (float*)d_out, B);
}

// Round 4
// 1210.414 us; speedup vs baseline: 1.2091x; 1.0535x over previous
//
#include <hip/hip_runtime.h>
#include <math.h>

// ---------------------------------------------------------------------------
// GP posterior mean:
//   k_outer : separable NUFFT outer products, fp32 atomic-free partials.
//   k_reduce: partials -> fp32 circulant table vcf + fp64 rhs b.
//   k_cg_solve: R17: Vf is REAL (v conj-symmetric => real spectrum; imag is
//     rounding noise ~1e-6 rel). Store Vf as float with 1/16384 folded in
//     (exact pow2 scale commutes with FFT bit-exactly):
//       - it_colB: 16 cmulf -> 16 real scales; Vf L2 bytes halved.
//       - dot phase: inv16384 fp64 muls removed.
//     R16: bfly16 twiddles as LOCAL const tables (SROA-folded immediates);
//     i_colA stores only rows<64. R15 lesson: VGPR budget pinned at 64 —
//     do NOT hoist arrays into registers (spills to scratch).
//     R14: CG-state remap (thread owns row tid>>4, cols (tid&15)+16s);
//     fused scatter+rowA and i_rowA+Ap; x in regs. 8 barriers/iter.
//     R12 lesson kept: scalar cmul + 2 separate reduces.
//   k_eval  : R17: T1 by fp64 complex recurrence (69 -> 4 fp64 sincospi per
//     thread; kernel is latency-exposed single-wave blocks).
// ---------------------------------------------------------------------------

typedef float f2 __attribute__((ext_vector_type(2)));
#define PB 16
#define RS 137          // Z row stride in f2 (8 blocks x 17)

__device__ inline f2 f2s(float s) { return (f2){s, s}; }
__device__ inline f2 cmulf(f2 a, f2 b) {   // a*b
    return (f2){a.x * b.x - a.y * b.y, a.x * b.y + a.y * b.x};
}
__device__ inline f2 cmulcf(f2 a, f2 b) {  // a*conj(b)
    return (f2){a.x * b.x + a.y * b.y, a.y * b.x - a.x * b.y};
}
__device__ inline int cpad(int c) { return (c >> 4) * 17 + (c & 15); }

// exp(i*pi*x*m) with fp64 angle reduction, scaled
__device__ inline f2 phasef(float xv, float m, float scale) {
    double ang = (double)xv * (double)m;
    double r = ang - 2.0 * rint(ang * 0.5);
    float sn, cs;
    sincospif((float)r, &sn, &cs);
    return (f2){cs * scale, sn * scale};
}

// ---------------------------------------------------------------------------
// k_outer (code unchanged — best-known config; (256,4) spills, R6)
// ---------------------------------------------------------------------------
__global__ __launch_bounds__(256, 2) void k_outer(const float* __restrict__ x,
                                                  const float* __restrict__ y,
                                                  float* __restrict__ pv,
                                                  float* __restrict__ pf,
                                                  int N, int cv, int cf)
{
    __shared__ f2 hs[PB][256];
    __shared__ float xs0[PB], xs1[PB], ys[PB];

    int bx = blockIdx.x;
    int t  = threadIdx.x;
    int ty = t >> 4, tx = t & 15;

    if (bx < cv) {
        int CP = (N + cv - 1) / cv;
        int n0 = bx * CP, n1 = min(N, n0 + CP);

        f2 acc[8][8];
        #pragma unroll
        for (int i = 0; i < 8; ++i)
            #pragma unroll
            for (int j = 0; j < 8; ++j) acc[i][j] = (f2){0.f, 0.f};

        for (int s = n0; s < n1; s += PB) {
            int cnt = min(PB, n1 - s);
            __syncthreads();
            if (t < cnt) {
                xs0[t] = x[2 * (s + t)];
                xs1[t] = x[2 * (s + t) + 1];
            }
            __syncthreads();
            for (int p = 0; p < cnt; ++p) {
                f2 g;
                if (t < 128)
                    g = (t == 127) ? (f2){0.f, 0.f} : phasef(xs0[p], (float)t - 63.f, 1.f);
                else {
                    int c = t - 128;
                    g = (c == 127) ? (f2){0.f, 0.f} : phasef(xs1[p], (float)c - 63.f, 1.f);
                }
                hs[p][t] = g;
            }
            __syncthreads();
            for (int p = 0; p < cnt; ++p) {
                f2 h1[8], h2[8], h2s[8];
                #pragma unroll
                for (int i = 0; i < 8; ++i) h1[i] = hs[p][ty * 8 + i];
                #pragma unroll
                for (int j = 0; j < 8; ++j) {
                    f2 b = hs[p][128 + tx + 16 * j];
                    h2[j] = b;
                    h2s[j] = (f2){-b.y, b.x};
                }
                #pragma unroll
                for (int i = 0; i < 8; ++i)
                    #pragma unroll
                    for (int j = 0; j < 8; ++j) {
                        acc[i][j] = acc[i][j] + f2s(h1[i].x) * h2[j];
                        acc[i][j] = acc[i][j] + f2s(h1[i].y) * h2s[j];
                    }
            }
        }
        __syncthreads();
        f2* out = (f2*)pv + (size_t)bx * 16384;
        #pragma unroll
        for (int i = 0; i < 8; ++i) {
            int a = ty * 8 + i;
            #pragma unroll
            for (int j = 0; j < 8; ++j)
                out[a * 128 + tx + 16 * j] = acc[i][j];
        }
    } else {
        int chunk = bx - cv;
        int CP = (N + cf - 1) / cf;
        int n0 = chunk * CP, n1 = min(N, n0 + CP);

        f2 acc[4][4];
        #pragma unroll
        for (int i = 0; i < 4; ++i)
            #pragma unroll
            for (int j = 0; j < 4; ++j) acc[i][j] = (f2){0.f, 0.f};

        for (int s = n0; s < n1; s += PB) {
            int cnt = min(PB, n1 - s);
            __syncthreads();
            if (t < cnt) {
                xs0[t] = x[2 * (s + t)];
                xs1[t] = x[2 * (s + t) + 1];
                ys[t]  = y[s + t];
            }
            __syncthreads();
            for (int p2 = 0; p2 < cnt; p2 += 2) {
                int p = p2 + (t >> 7);
                int c = t & 127;
                if (p < cnt) {
                    f2 g;
                    if (c < 64) g = phasef(xs0[p], (float)(32 - c), ys[p]);
                    else        g = phasef(xs1[p], (float)(32 - (c - 64)), 1.f);
                    hs[p][c] = g;
                }
            }
            __syncthreads();
            for (int p = 0; p < cnt; ++p) {
                f2 h1[4], h2[4], h2s[4];
                #pragma unroll
                for (int i = 0; i < 4; ++i) h1[i] = hs[p][ty * 4 + i];
                #pragma unroll
                for (int j = 0; j < 4; ++j) {
                    f2 b = hs[p][64 + tx + 16 * j];
                    h2[j] = b;
                    h2s[j] = (f2){-b.y, b.x};
                }
                #pragma unroll
                for (int i = 0; i < 4; ++i)
                    #pragma unroll
                    for (int j = 0; j < 4; ++j) {
                        acc[i][j] = acc[i][j] + f2s(h1[i].x) * h2[j];
                        acc[i][j] = acc[i][j] + f2s(h1[i].y) * h2s[j];
                    }
            }
        }
        __syncthreads();
        f2* out = (f2*)pf + (size_t)chunk * 4096;
        #pragma unroll
        for (int i = 0; i < 4; ++i) {
            int a = ty * 4 + i;
            #pragma unroll
            for (int j = 0; j < 4; ++j)
                out[a * 64 + tx + 16 * j] = acc[i][j];
        }
    }
}

// ---------------------------------------------------------------------------
// k_reduce (unchanged): partials -> circulant vcf (fp32) + rvec = ws*Fy (fp64)
// ---------------------------------------------------------------------------
__global__ __launch_bounds__(256) void k_reduce(const float* __restrict__ pv,
                                                const float* __restrict__ pf,
                                                const float* __restrict__ wsv,
                                                float* __restrict__ vcf,
                                                double2* __restrict__ rvec,
                                                int cv, int cf)
{
    int id = blockIdx.x * 256 + threadIdx.x;
    if (id < 131072) {
        int e = id >> 3, sl = id & 7;
        int q1 = e >> 7, q2 = e & 127;
        int a = (q1 + 63) & 127, b = (q2 + 63) & 127;
        int cn = cv >> 3;
        const float* src = pv + (size_t)(a * 128 + b) * 2
                              + (size_t)(sl * cn) * 32768;
        float sx = 0.f, sy = 0.f;
        for (int c = 0; c < cn; ++c) { sx += src[0]; sy += src[1]; src += 32768; }
        atomicAdd(&vcf[e * 2], sx);
        atomicAdd(&vcf[e * 2 + 1], sy);
    } else {
        int e = id - 131072;
        const float* s2p = pf + (size_t)e * 2;
        double fx = 0.0, fy2 = 0.0;
        for (int c = 0; c < cf; ++c) { fx += (double)s2p[0]; fy2 += (double)s2p[1]; s2p += 8192; }
        double w = (double)wsv[e];
        rvec[e] = make_double2(w * fx, w * fy2);
    }
}

// ---------------------------------------------------------------------------
// Fused-stage FFT passes, STATIC register indexing only.
// Z[r*RS + cpad(c)], RS=137. tw[t] = exp(-i*pi*t/64) = W_128^t.
// bfly16 twiddles are lane-uniform -> LOCAL const tables (SROA-folded to
// immediates after unroll; no LDS / no constant-mem traffic).
// ---------------------------------------------------------------------------
#define TC1 0.92387953251128676f   // cos(pi/8)
#define TS1 0.38268343236508977f   // sin(pi/8)
#define TSQ 0.70710678118654752f   // sqrt(2)/2

__device__ inline void bflyA_fwd(f2* L, const f2* tw, int b) {
    #pragma unroll
    for (int s = 0; s < 4; ++s) {                    // h=64
        f2 u0 = L[s], v0 = L[s + 4];
        L[s] = u0 + v0;
        L[s + 4] = cmulf(u0 - v0, tw[b + 16 * s]);
    }
    const int ss[4] = {0, 1, 4, 5};
    #pragma unroll
    for (int q = 0; q < 4; ++q) {                    // h=32
        int s = ss[q];
        f2 u0 = L[s], v0 = L[s + 2];
        L[s] = u0 + v0;
        L[s + 2] = cmulf(u0 - v0, tw[2 * b + 32 * (s & 1)]);
    }
    #pragma unroll
    for (int s = 0; s < 8; s += 2) {                 // h=16
        f2 u0 = L[s], v0 = L[s + 1];
        L[s] = u0 + v0;
        L[s + 1] = cmulf(u0 - v0, tw[4 * b]);
    }
}
__device__ inline void bflyA_inv(f2* L, const f2* tw, int b) {
    #pragma unroll
    for (int s = 0; s < 8; s += 2) {                 // h=16
        f2 u0 = L[s];
        f2 vw = cmulcf(L[s + 1], tw[4 * b]);
        L[s] = u0 + vw; L[s + 1] = u0 - vw;
    }
    const int ss[4] = {0, 1, 4, 5};
    #pragma unroll
    for (int q = 0; q < 4; ++q) {                    // h=32
        int s = ss[q];
        f2 u0 = L[s];
        f2 vw = cmulcf(L[s + 2], tw[2 * b + 32 * (s & 1)]);
        L[s] = u0 + vw; L[s + 2] = u0 - vw;
    }
    #pragma unroll
    for (int s = 0; s < 4; ++s) {                    // h=64
        f2 u0 = L[s];
        f2 vw = cmulcf(L[s + 4], tw[b + 16 * s]);
        L[s] = u0 + vw; L[s + 4] = u0 - vw;
    }
}
__device__ inline void bfly16_fwd(f2* M) {
    const float c8x[8]  = {1.f, TC1, TSQ, TS1, 0.f, -TS1, -TSQ, -TC1};
    const float c8y[8]  = {0.f, -TS1, -TSQ, -TC1, -1.f, -TC1, -TSQ, -TS1};
    const float c16x[4] = {1.f, TSQ, 0.f, -TSQ};
    const float c16y[4] = {0.f, -TSQ, -1.f, -TSQ};
    #pragma unroll
    for (int s = 0; s < 8; ++s) {                    // h=8
        f2 u0 = M[s], v0 = M[s + 8];
        M[s] = u0 + v0;
        M[s + 8] = cmulf(u0 - v0, (f2){c8x[s], c8y[s]});
    }
    #pragma unroll
    for (int q = 0; q < 8; ++q) {                    // h=4
        int s = (q & 3) + 8 * (q >> 2);
        f2 u0 = M[s], v0 = M[s + 4];
        M[s] = u0 + v0;
        M[s + 4] = cmulf(u0 - v0, (f2){c16x[s & 3], c16y[s & 3]});
    }
    #pragma unroll
    for (int q = 0; q < 8; ++q) {                    // h=2
        int s = (q & 1) + 4 * (q >> 1);
        f2 u0 = M[s], v0 = M[s + 2];
        M[s] = u0 + v0;
        f2 d = u0 - v0;
        M[s + 2] = (s & 1) ? (f2){d.y, -d.x} : d;    // * (0,-1) or * 1
    }
    #pragma unroll
    for (int s = 0; s < 16; s += 2) {                // h=1
        f2 u0 = M[s], v0 = M[s + 1];
        M[s] = u0 + v0; M[s + 1] = u0 - v0;
    }
}
__device__ inline void bfly16_inv(f2* M) {
    const float c8x[8]  = {1.f, TC1, TSQ, TS1, 0.f, -TS1, -TSQ, -TC1};
    const float c8y[8]  = {0.f, -TS1, -TSQ, -TC1, -1.f, -TC1, -TSQ, -TS1};
    const float c16x[4] = {1.f, TSQ, 0.f, -TSQ};
    const float c16y[4] = {0.f, -TSQ, -1.f, -TSQ};
    #pragma unroll
    for (int s = 0; s < 16; s += 2) {                // h=1
        f2 u0 = M[s], v0 = M[s + 1];
        M[s] = u0 + v0; M[s + 1] = u0 - v0;
    }
    #pragma unroll
    for (int q = 0; q < 8; ++q) {                    // h=2
        int s = (q & 1) + 4 * (q >> 1);
        f2 u0 = M[s];
        f2 v0 = M[s + 2];
        f2 vw = (s & 1) ? (f2){-v0.y, v0.x} : v0;    // conj(0,-1) = (0,1)
        M[s] = u0 + vw; M[s + 2] = u0 - vw;
    }
    #pragma unroll
    for (int q = 0; q < 8; ++q) {                    // h=4
        int s = (q & 3) + 8 * (q >> 2);
        f2 u0 = M[s];
        f2 vw = cmulcf(M[s + 4], (f2){c16x[s & 3], c16y[s & 3]});
        M[s] = u0 + vw; M[s + 4] = u0 - vw;
    }
    #pragma unroll
    for (int s = 0; s < 8; ++s) {                    // h=8
        f2 u0 = M[s];
        f2 vw = cmulcf(M[s + 8], (f2){c8x[s], c8y[s]});
        M[s] = u0 + vw; M[s + 8] = u0 - vw;
    }
}

__device__ inline void f_rowA(f2* Z, const f2* tw, int tid, int nrows, bool zup) {
    for (int u = tid; u < nrows * 16; u += 1024) {
        int r = u >> 4, b = u & 15;
        f2* row = Z + r * RS;
        f2 L[8];
        #pragma unroll
        for (int s = 0; s < 4; ++s) L[s] = row[17 * s + b];
        if (zup) {
            #pragma unroll
            for (int s = 4; s < 8; ++s) L[s] = (f2){0.f, 0.f};
        } else {
            #pragma unroll
            for (int s = 4; s < 8; ++s) L[s] = row[17 * s + b];
        }
        bflyA_fwd(L, tw, b);
        #pragma unroll
        for (int s = 0; s < 8; ++s) row[17 * s + b] = L[s];
    }
}
__device__ inline void f_rowB(f2* Z, int tid, int nrows) {
    for (int u = tid; u < nrows * 8; u += 1024) {
        int r = u >> 3, g = u & 7;
        f2* blk = Z + r * RS + g * 17;
        f2 M[16];
        #pragma unroll
        for (int s = 0; s < 16; ++s) M[s] = blk[s];
        bfly16_fwd(M);
        #pragma unroll
        for (int s = 0; s < 16; ++s) blk[s] = M[s];
    }
}
__device__ inline void i_rowB(f2* Z, int tid, int nrows) {
    for (int u = tid; u < nrows * 8; u += 1024) {
        int r = u >> 3, g = u & 7;
        f2* blk = Z + r * RS + g * 17;
        f2 M[16];
        #pragma unroll
        for (int s = 0; s < 16; ++s) M[s] = blk[s];
        bfly16_inv(M);
        #pragma unroll
        for (int s = 0; s < 16; ++s) blk[s] = M[s];
    }
}
__device__ inline void f_colA(f2* Z, const f2* tw, int tid, bool zup) {
    for (int u = tid; u < 2048; u += 1024) {
        int c = u >> 4, b = u & 15;
        int cp = cpad(c);
        f2 L[8];
        #pragma unroll
        for (int s = 0; s < 4; ++s) L[s] = Z[(b + 16 * s) * RS + cp];
        if (zup) {
            #pragma unroll
            for (int s = 4; s < 8; ++s) L[s] = (f2){0.f, 0.f};
        } else {
            #pragma unroll
            for (int s = 4; s < 8; ++s) L[s] = Z[(b + 16 * s) * RS + cp];
        }
        bflyA_fwd(L, tw, b);
        #pragma unroll
        for (int s = 0; s < 8; ++s) Z[(b + 16 * s) * RS + cp] = L[s];
    }
}
// i_colA: only rows<64 of the output are consumed downstream -> store s<4.
__device__ inline void i_colA(f2* Z, const f2* tw, int tid) {
    for (int u = tid; u < 2048; u += 1024) {
        int c = u >> 4, b = u & 15;
        int cp = cpad(c);
        f2 L[8];
        #pragma unroll
        for (int s = 0; s < 8; ++s) L[s] = Z[(b + 16 * s) * RS + cp];
        bflyA_inv(L, tw, b);
        #pragma unroll
        for (int s = 0; s < 4; ++s) Z[(b + 16 * s) * RS + cp] = L[s];
    }
}
// colB: lanes span 64 columns (c = tid&127) so banks vary across a wave.
__device__ inline void f_colB(f2* Z, int tid) {        // setup
    int c = tid & 127, g = tid >> 7;
    f2* col = Z + g * 16 * RS + cpad(c);
    f2 M[16];
    #pragma unroll
    for (int s = 0; s < 16; ++s) M[s] = col[s * RS];
    bfly16_fwd(M);
    #pragma unroll
    for (int s = 0; s < 16; ++s) col[s * RS] = M[s];
}
// it_colB: Vf is REAL float (1/16384 pre-folded) — 16 real scales.
__device__ inline void it_colB(f2* Z, const float* Vfg, int tid) {
    int c = tid & 127, g = tid >> 7;
    f2* col = Z + g * 16 * RS + cpad(c);
    const float* vf = Vfg + g * 16 * 128 + c;
    f2 M[16];
    #pragma unroll
    for (int s = 0; s < 16; ++s) M[s] = col[s * RS];
    bfly16_fwd(M);
    #pragma unroll
    for (int s = 0; s < 16; ++s) M[s] = M[s] * f2s(vf[s * 128]);
    bfly16_inv(M);
    #pragma unroll
    for (int s = 0; s < 16; ++s) col[s * RS] = M[s];
}

// One-barrier block reduce: >=1 barrier separates reuses of the same buffer.
__device__ inline double blk_reduce(double v, double* red, int wid, int m) {
    #pragma unroll
    for (int off = 32; off > 0; off >>= 1) v += __shfl_down(v, off);
    if (m == 0) red[wid] = v;
    __syncthreads();
    double s = 0.0;
    #pragma unroll
    for (int i = 0; i < 16; ++i) s += red[i];
    return s;
}

// ---------------------------------------------------------------------------
// k_cg_solve: R17 (see header). Thread tid owns elements
//   e_s = (tid>>4)*64 + (tid&15) + 16s  (row r=tid>>4, cols b+16s)
// ---------------------------------------------------------------------------
__global__ __launch_bounds__(1024, 4) void k_cg_solve(
        const float* __restrict__ vcf, float* __restrict__ Vf,
        const double2* __restrict__ rvec, const float* __restrict__ wsv,
        const float* __restrict__ sig2, float* __restrict__ alg)
{
    __shared__ f2 Z[128 * RS];
    __shared__ f2 tw[64];
    __shared__ double redA[16], redB[16], redC[16];

    int tid = threadIdx.x;
    int wid = tid >> 6, m = tid & 63;
    int rr_ = tid >> 4, bb_ = tid & 15;          // this thread's rowA unit

    if (tid < 64) {
        float sn, cs;
        sincospif(-(float)tid / 64.f, &sn, &cs);
        tw[tid] = (f2){cs, sn};
    }
    __syncthreads();

    // ---- Vf setup (forward transform of vc, scrambled order).
    //      Store REAL part only, scaled by 1/16384 (exact pow2).
    for (int i = tid; i < 16384; i += 1024)
        Z[(i >> 7) * RS + cpad(i & 127)] = ((const f2*)vcf)[i];
    __syncthreads();
    f_rowA(Z, tw, tid, 128, false); __syncthreads();
    f_rowB(Z, tid, 128);            __syncthreads();
    f_colA(Z, tw, tid, false);      __syncthreads();
    f_colB(Z, tid);                 __syncthreads();
    for (int i = tid; i < 16384; i += 1024)
        Vf[i] = Z[(i >> 7) * RS + cpad(i & 127)].x * (1.f / 16384.f);
    __syncthreads();

    // ---- CG state (p, r, x all in regs; element e_s = rr_*64 + bb_ + 16s)
    double2 pR[4], rR[4], xR[4];
    float wsr[4];
    double rzp = 0.0;
    #pragma unroll
    for (int s = 0; s < 4; ++s) {
        int e = rr_ * 64 + bb_ + (s << 4);
        double2 bv = rvec[e];
        pR[s] = bv; rR[s] = bv;
        xR[s] = make_double2(0.0, 0.0);
        wsr[s] = wsv[e];
        rzp += bv.x * bv.x + bv.y * bv.y;
    }
    double rz = blk_reduce(rzp, redC, wid, m);
    double s2 = (double)sig2[0];
    __syncthreads();

    for (int it = 0; it < 50; ++it) {
        // ---- fused scatter + forward rowA: z = ws*p from regs (zero-padded)
        {
            f2* row = Z + rr_ * RS;
            f2 L[8];
            #pragma unroll
            for (int s = 0; s < 4; ++s)
                L[s] = (f2){(float)((double)wsr[s] * pR[s].x),
                            (float)((double)wsr[s] * pR[s].y)};
            #pragma unroll
            for (int s = 4; s < 8; ++s) L[s] = (f2){0.f, 0.f};
            bflyA_fwd(L, tw, bb_);
            #pragma unroll
            for (int s = 0; s < 8; ++s) row[17 * s + bb_] = L[s];
        }
        __syncthreads();

        f_rowB(Z, tid, 64);                      __syncthreads();
        f_colA(Z, tw, tid, true);                __syncthreads();
        it_colB(Z, Vf, tid);                     __syncthreads();
        i_colA(Z, tw, tid);                      __syncthreads();
        i_rowB(Z, tid, 64);                      __syncthreads();

        // ---- fused inverse rowA + Ap extraction (L[0..3] are our elements;
        //      unused upper-half outputs dead-code-eliminate).
        //      az is pre-scaled by 1/16384 (folded into Vf).
        f2 az[4];
        {
            f2* row = Z + rr_ * RS;
            f2 L[8];
            #pragma unroll
            for (int s = 0; s < 8; ++s) L[s] = row[17 * s + bb_];
            bflyA_inv(L, tw, bb_);
            #pragma unroll
            for (int s = 0; s < 4; ++s) az[s] = L[s];
        }
        double papp = 0.0;
        #pragma unroll
        for (int s = 0; s < 4; ++s) {
            double apx = (double)wsr[s] * (double)az[s].x + s2 * pR[s].x;
            double apy = (double)wsr[s] * (double)az[s].y + s2 * pR[s].y;
            papp += pR[s].x * apx + pR[s].y * apy;
        }
        double pap = blk_reduce(papp, redA, wid, m);
        double alpha = rz / (pap + 1e-30);

        double rrp = 0.0;
        #pragma unroll
        for (int s = 0; s < 4; ++s) {
            double apx = (double)wsr[s] * (double)az[s].x + s2 * pR[s].x;
            double apy = (double)wsr[s] * (double)az[s].y + s2 * pR[s].y;
            xR[s].x += alpha * pR[s].x; xR[s].y += alpha * pR[s].y;
            rR[s].x -= alpha * apx; rR[s].y -= alpha * apy;
            rrp += rR[s].x * rR[s].x + rR[s].y * rR[s].y;
        }
        double rzn = blk_reduce(rrp, redB, wid, m);
        double beta = rzn / (rz + 1e-30);
        rz = rzn;
        #pragma unroll
        for (int s = 0; s < 4; ++s) {
            pR[s].x = rR[s].x + beta * pR[s].x;
            pR[s].y = rR[s].y + beta * pR[s].y;
        }
    }

    // al = ws * x_50
    #pragma unroll
    for (int s = 0; s < 4; ++s) {
        int e = rr_ * 64 + bb_ + (s << 4);
        ((f2*)alg)[e] = (f2){(float)((double)wsr[s] * xR[s].x),
                             (float)((double)wsr[s] * xR[s].y)};
    }
}

// ---------------------------------------------------------------------------
// k_eval: R17 — T1 via fp64 complex recurrence (j ascending across jg),
// e2 jg-init hoisted (identical every jg). 69 -> 4 fp64 sincospi/thread.
// ---------------------------------------------------------------------------
__global__ __launch_bounds__(64) void k_eval(const float* __restrict__ xnew,
                                             const float* __restrict__ alg,
                                             float* __restrict__ out, int B)
{
    __shared__ float2 al[4096];
    int t = threadIdx.x;
    int b = blockIdx.x * 64 + t;
    for (int i = t; i < 4096; i += 64) {
        f2 v = ((const f2*)alg)[i];
        al[i] = make_float2(v.x, v.y);
    }
    float x0 = 0.f, x1 = 0.f;
    if (b < B) { x0 = xnew[2 * b]; x1 = xnew[2 * b + 1]; }
    __syncthreads();
    double2 wstep; { double sn, cs; sincospi((double)x1, &sn, &cs); wstep = make_double2(cs, sn); }
    double2 e2_0;  { double sn, cs; sincospi(-32.0 * (double)x1, &sn, &cs); e2_0 = make_double2(cs, sn); }
    double2 w1;    { double sn, cs; sincospi((double)x0, &sn, &cs); w1 = make_double2(cs, sn); }
    double2 e1;    { double sn, cs; sincospi(-32.0 * (double)x0, &sn, &cs); e1 = make_double2(cs, sn); }
    double mu = 0.0;
    for (int jg = 0; jg < 4; ++jg) {
        float2 tacc[16];
        for (int q = 0; q < 16; ++q) tacc[q] = make_float2(0.f, 0.f);
        double2 e2 = e2_0;
        for (int k = 0; k < 64; ++k) {
            float2 e2f = make_float2((float)e2.x, (float)e2.y);
            for (int q = 0; q < 16; ++q) {
                int j = jg * 16 + q;
                float2 a = al[j * 64 + k];
                tacc[q].x += a.x * e2f.x - a.y * e2f.y;
                tacc[q].y += a.x * e2f.y + a.y * e2f.x;
            }
            e2 = make_double2(e2.x * wstep.x - e2.y * wstep.y,
                              e2.x * wstep.y + e2.y * wstep.x);
        }
        for (int q = 0; q < 16; ++q) {
            mu += e1.x * (double)tacc[q].x - e1.y * (double)tacc[q].y;
            e1 = make_double2(e1.x * w1.x - e1.y * w1.y,
                              e1.x * w1.y + e1.y * w1.x);
        }
    }
    if (b < B) out[b] = (float)mu;
}

// ---------------------------------------------------------------------------

extern "C" void kernel_launch(void* const* d_in, const int* in_sizes, int n_in,
                              void* d_out, int out_size, void* d_ws, size_t ws_size,
                              hipStream_t stream)
{
    const float* x    = (const float*)d_in[0];
    const float* y    = (const float*)d_in[1];
    const float* xnew = (const float*)d_in[2];
    const float* wsv  = (const float*)d_in[3];
    const float* sig2 = (const float*)d_in[4];
    int N = in_sizes[1];
    int B = in_sizes[2] / 2;

    char* base = (char*)d_ws;
    size_t o = 0;
    float*   vcf  = (float*)(base + o);   o += 131072;   // 128x128 circulant vc (fp32)
    float*   Vf   = (float*)(base + o);   o += 65536;    // REAL FFT of vc, /16384 folded
    double2* rvec = (double2*)(base + o); o += 65536;    // b = ws*Fy (fp64)
    float*   alg  = (float*)(base + o);   o += 32768;    // ws*x_50 (fp32 complex)
    size_t avail = (ws_size > o) ? ws_size - o : 0;
    int cv = (int)(avail / 139264);                      // 128KB v + 8KB fy per unit
    if (cv > 768) cv = 768;                              // R13: raised 384->768
    if (cv < 16) cv = 16;                                //   (grid was the
    cv &= ~15;                                           //    occupancy binder)
    int cf = cv / 4;
    float* pv = (float*)(base + o); o += (size_t)cv * 131072;
    float* pf = (float*)(base + o);

    hipMemsetAsync(vcf, 0, 131072, stream);              // fp32 atomic target

    k_outer<<<cv + cf, 256, 0, stream>>>(x, y, pv, pf, N, cv, cf);
    k_reduce<<<528, 256, 0, stream>>>(pv, pf, wsv, vcf, rvec, cv, cf);
    k_cg_solve<<<1, 1024, 0, stream>>>(vcf, Vf, rvec, wsv, sig2, alg);
    k_eval<<<(B + 63) / 64, 64, 0, stream>>>(xnew, alg, (float*)d_out, B);
}

// Round 5
// 1143.190 us; speedup vs baseline: 1.2802x; 1.0588x over previous
//
#include <hip/hip_runtime.h>
#include <math.h>

// ---------------------------------------------------------------------------
// GP posterior mean:
//   k_outer : R18: v is conj-symmetric (v[-p] = conj(v[p]) bit-exactly) ->
//     v-part computes only rows p1 in [0,63]: 64x128 grid (half FLOPs,
//     half pv traffic, acc 128->64 VGPR). f-part unchanged.
//   k_reduce: R18: reconstructs the full circulant table from the half
//     grid — each stored entry writes its position AND its conj mirror
//     (p1==0 guarded; vcf row/col 64 stay memset-zero as before).
//   k_cg_solve: R17-exact (737us verified): Vf REAL fp32 with 1/16384
//     folded; bfly16 twiddles as local const tables (R16); i_colA half
//     store; CG-state remap + fused scatter/rowA + i_rowA/Ap (R14);
//     8 barriers/iter. R15 lesson: VGPR budget pinned at 64 — do NOT
//     hoist arrays into registers (scratch spills).
//   k_eval  : R17-exact: fp64 complex recurrences, 4 sincospi/thread.
// ---------------------------------------------------------------------------

typedef float f2 __attribute__((ext_vector_type(2)));
#define PB 16
#define RS 137          // Z row stride in f2 (8 blocks x 17)

__device__ inline f2 f2s(float s) { return (f2){s, s}; }
__device__ inline f2 cmulf(f2 a, f2 b) {   // a*b
    return (f2){a.x * b.x - a.y * b.y, a.x * b.y + a.y * b.x};
}
__device__ inline f2 cmulcf(f2 a, f2 b) {  // a*conj(b)
    return (f2){a.x * b.x + a.y * b.y, a.y * b.x - a.x * b.y};
}
__device__ inline int cpad(int c) { return (c >> 4) * 17 + (c & 15); }

// exp(i*pi*x*m) with fp64 angle reduction, scaled
__device__ inline f2 phasef(float xv, float m, float scale) {
    double ang = (double)xv * (double)m;
    double r = ang - 2.0 * rint(ang * 0.5);
    float sn, cs;
    sincospif((float)r, &sn, &cs);
    return (f2){cs * scale, sn * scale};
}

// ---------------------------------------------------------------------------
// k_outer: v-part computes HALF grid (rows p1=0..63, cols p2=-63..63;
// col slot 127 zero). Layout hs[p][0..63]=row phases, [64..191]=col phases.
// ---------------------------------------------------------------------------
__global__ __launch_bounds__(256, 2) void k_outer(const float* __restrict__ x,
                                                  const float* __restrict__ y,
                                                  float* __restrict__ pv,
                                                  float* __restrict__ pf,
                                                  int N, int cv, int cf)
{
    __shared__ f2 hs[PB][256];
    __shared__ float xs0[PB], xs1[PB], ys[PB];

    int bx = blockIdx.x;
    int t  = threadIdx.x;
    int ty = t >> 4, tx = t & 15;

    if (bx < cv) {
        int CP = (N + cv - 1) / cv;
        int n0 = bx * CP, n1 = min(N, n0 + CP);

        f2 acc[4][8];
        #pragma unroll
        for (int i = 0; i < 4; ++i)
            #pragma unroll
            for (int j = 0; j < 8; ++j) acc[i][j] = (f2){0.f, 0.f};

        for (int s = n0; s < n1; s += PB) {
            int cnt = min(PB, n1 - s);
            __syncthreads();
            if (t < cnt) {
                xs0[t] = x[2 * (s + t)];
                xs1[t] = x[2 * (s + t) + 1];
            }
            __syncthreads();
            for (int p = 0; p < cnt; ++p) {
                if (t < 192) {
                    f2 g;
                    if (t < 64)
                        g = phasef(xs0[p], (float)t, 1.f);              // p1 = t
                    else
                        g = (t == 191) ? (f2){0.f, 0.f}
                                       : phasef(xs1[p], (float)(t - 127), 1.f); // p2 = t-127
                    hs[p][t] = g;
                }
            }
            __syncthreads();
            for (int p = 0; p < cnt; ++p) {
                f2 h1[4], h2[8], h2s[8];
                #pragma unroll
                for (int i = 0; i < 4; ++i) h1[i] = hs[p][ty * 4 + i];
                #pragma unroll
                for (int j = 0; j < 8; ++j) {
                    f2 b = hs[p][64 + tx + 16 * j];
                    h2[j] = b;
                    h2s[j] = (f2){-b.y, b.x};
                }
                #pragma unroll
                for (int i = 0; i < 4; ++i)
                    #pragma unroll
                    for (int j = 0; j < 8; ++j) {
                        acc[i][j] = acc[i][j] + f2s(h1[i].x) * h2[j];
                        acc[i][j] = acc[i][j] + f2s(h1[i].y) * h2s[j];
                    }
            }
        }
        __syncthreads();
        f2* out = (f2*)pv + (size_t)bx * 8192;           // 64x128 f2 = 64KB
        #pragma unroll
        for (int i = 0; i < 4; ++i) {
            int a = ty * 4 + i;
            #pragma unroll
            for (int j = 0; j < 8; ++j)
                out[a * 128 + tx + 16 * j] = acc[i][j];
        }
    } else {
        int chunk = bx - cv;
        int CP = (N + cf - 1) / cf;
        int n0 = chunk * CP, n1 = min(N, n0 + CP);

        f2 acc[4][4];
        #pragma unroll
        for (int i = 0; i < 4; ++i)
            #pragma unroll
            for (int j = 0; j < 4; ++j) acc[i][j] = (f2){0.f, 0.f};

        for (int s = n0; s < n1; s += PB) {
            int cnt = min(PB, n1 - s);
            __syncthreads();
            if (t < cnt) {
                xs0[t] = x[2 * (s + t)];
                xs1[t] = x[2 * (s + t) + 1];
                ys[t]  = y[s + t];
            }
            __syncthreads();
            for (int p2 = 0; p2 < cnt; p2 += 2) {
                int p = p2 + (t >> 7);
                int c = t & 127;
                if (p < cnt) {
                    f2 g;
                    if (c < 64) g = phasef(xs0[p], (float)(32 - c), ys[p]);
                    else        g = phasef(xs1[p], (float)(32 - (c - 64)), 1.f);
                    hs[p][c] = g;
                }
            }
            __syncthreads();
            for (int p = 0; p < cnt; ++p) {
                f2 h1[4], h2[4], h2s[4];
                #pragma unroll
                for (int i = 0; i < 4; ++i) h1[i] = hs[p][ty * 4 + i];
                #pragma unroll
                for (int j = 0; j < 4; ++j) {
                    f2 b = hs[p][64 + tx + 16 * j];
                    h2[j] = b;
                    h2s[j] = (f2){-b.y, b.x};
                }
                #pragma unroll
                for (int i = 0; i < 4; ++i)
                    #pragma unroll
                    for (int j = 0; j < 4; ++j) {
                        acc[i][j] = acc[i][j] + f2s(h1[i].x) * h2[j];
                        acc[i][j] = acc[i][j] + f2s(h1[i].y) * h2s[j];
                    }
            }
        }
        __syncthreads();
        f2* out = (f2*)pf + (size_t)chunk * 4096;
        #pragma unroll
        for (int i = 0; i < 4; ++i) {
            int a = ty * 4 + i;
            #pragma unroll
            for (int j = 0; j < 4; ++j)
                out[a * 64 + tx + 16 * j] = acc[i][j];
        }
    }
}

// ---------------------------------------------------------------------------
// k_reduce: R18. v-part sums the half-grid entry (p1,b) over chunks and
// writes BOTH circulant positions:
//   direct: q1 = p1,        q2 = (b+65)&127,  value (sx,  sy)
//   mirror: q1 = 128-p1,    q2 = (63-b)&127,  value (sx, -sy)   [p1>0 only]
// vcf row/col q=64 stay memset-zero (p1=64 / p2=64 slots, zero as before).
// ---------------------------------------------------------------------------
__global__ __launch_bounds__(256) void k_reduce(const float* __restrict__ pv,
                                                const float* __restrict__ pf,
                                                const float* __restrict__ wsv,
                                                float* __restrict__ vcf,
                                                double2* __restrict__ rvec,
                                                int cv, int cf)
{
    int id = blockIdx.x * 256 + threadIdx.x;
    if (id < 65536) {
        int e = id >> 3, sl = id & 7;        // e: p1 = e>>7 (0..63), b = e&127
        int cn = cv >> 3;
        const float* src = pv + (size_t)e * 2 + (size_t)(sl * cn) * 16384;
        float sx = 0.f, sy = 0.f;
        for (int c = 0; c < cn; ++c) { sx += src[0]; sy += src[1]; src += 16384; }
        int p1 = e >> 7, b = e & 127;
        int q2 = (b + 65) & 127;
        atomicAdd(&vcf[(p1 * 128 + q2) * 2],     sx);
        atomicAdd(&vcf[(p1 * 128 + q2) * 2 + 1], sy);
        if (p1 > 0) {
            int q1m = 128 - p1, q2m = (63 - b) & 127;
            atomicAdd(&vcf[(q1m * 128 + q2m) * 2],     sx);
            atomicAdd(&vcf[(q1m * 128 + q2m) * 2 + 1], -sy);
        }
    } else {
        int e = id - 65536;
        const float* s2p = pf + (size_t)e * 2;
        double fx = 0.0, fy2 = 0.0;
        for (int c = 0; c < cf; ++c) { fx += (double)s2p[0]; fy2 += (double)s2p[1]; s2p += 8192; }
        double w = (double)wsv[e];
        rvec[e] = make_double2(w * fx, w * fy2);
    }
}

// ---------------------------------------------------------------------------
// Fused-stage FFT passes, STATIC register indexing only.
// Z[r*RS + cpad(c)], RS=137. tw[t] = exp(-i*pi*t/64) = W_128^t.
// bfly16 twiddles are lane-uniform -> LOCAL const tables (SROA-folded to
// immediates after unroll; no LDS / no constant-mem traffic).
// ---------------------------------------------------------------------------
#define TC1 0.92387953251128676f   // cos(pi/8)
#define TS1 0.38268343236508977f   // sin(pi/8)
#define TSQ 0.70710678118654752f   // sqrt(2)/2

__device__ inline void bflyA_fwd(f2* L, const f2* tw, int b) {
    #pragma unroll
    for (int s = 0; s < 4; ++s) {                    // h=64
        f2 u0 = L[s], v0 = L[s + 4];
        L[s] = u0 + v0;
        L[s + 4] = cmulf(u0 - v0, tw[b + 16 * s]);
    }
    const int ss[4] = {0, 1, 4, 5};
    #pragma unroll
    for (int q = 0; q < 4; ++q) {                    // h=32
        int s = ss[q];
        f2 u0 = L[s], v0 = L[s + 2];
        L[s] = u0 + v0;
        L[s + 2] = cmulf(u0 - v0, tw[2 * b + 32 * (s & 1)]);
    }
    #pragma unroll
    for (int s = 0; s < 8; s += 2) {                 // h=16
        f2 u0 = L[s], v0 = L[s + 1];
        L[s] = u0 + v0;
        L[s + 1] = cmulf(u0 - v0, tw[4 * b]);
    }
}
__device__ inline void bflyA_inv(f2* L, const f2* tw, int b) {
    #pragma unroll
    for (int s = 0; s < 8; s += 2) {                 // h=16
        f2 u0 = L[s];
        f2 vw = cmulcf(L[s + 1], tw[4 * b]);
        L[s] = u0 + vw; L[s + 1] = u0 - vw;
    }
    const int ss[4] = {0, 1, 4, 5};
    #pragma unroll
    for (int q = 0; q < 4; ++q) {                    // h=32
        int s = ss[q];
        f2 u0 = L[s];
        f2 vw = cmulcf(L[s + 2], tw[2 * b + 32 * (s & 1)]);
        L[s] = u0 + vw; L[s + 2] = u0 - vw;
    }
    #pragma unroll
    for (int s = 0; s < 4; ++s) {                    // h=64
        f2 u0 = L[s];
        f2 vw = cmulcf(L[s + 4], tw[b + 16 * s]);
        L[s] = u0 + vw; L[s + 4] = u0 - vw;
    }
}
__device__ inline void bfly16_fwd(f2* M) {
    const float c8x[8]  = {1.f, TC1, TSQ, TS1, 0.f, -TS1, -TSQ, -TC1};
    const float c8y[8]  = {0.f, -TS1, -TSQ, -TC1, -1.f, -TC1, -TSQ, -TS1};
    const float c16x[4] = {1.f, TSQ, 0.f, -TSQ};
    const float c16y[4] = {0.f, -TSQ, -1.f, -TSQ};
    #pragma unroll
    for (int s = 0; s < 8; ++s) {                    // h=8
        f2 u0 = M[s], v0 = M[s + 8];
        M[s] = u0 + v0;
        M[s + 8] = cmulf(u0 - v0, (f2){c8x[s], c8y[s]});
    }
    #pragma unroll
    for (int q = 0; q < 8; ++q) {                    // h=4
        int s = (q & 3) + 8 * (q >> 2);
        f2 u0 = M[s], v0 = M[s + 4];
        M[s] = u0 + v0;
        M[s + 4] = cmulf(u0 - v0, (f2){c16x[s & 3], c16y[s & 3]});
    }
    #pragma unroll
    for (int q = 0; q < 8; ++q) {                    // h=2
        int s = (q & 1) + 4 * (q >> 1);
        f2 u0 = M[s], v0 = M[s + 2];
        M[s] = u0 + v0;
        f2 d = u0 - v0;
        M[s + 2] = (s & 1) ? (f2){d.y, -d.x} : d;    // * (0,-1) or * 1
    }
    #pragma unroll
    for (int s = 0; s < 16; s += 2) {                // h=1
        f2 u0 = M[s], v0 = M[s + 1];
        M[s] = u0 + v0; M[s + 1] = u0 - v0;
    }
}
__device__ inline void bfly16_inv(f2* M) {
    const float c8x[8]  = {1.f, TC1, TSQ, TS1, 0.f, -TS1, -TSQ, -TC1};
    const float c8y[8]  = {0.f, -TS1, -TSQ, -TC1, -1.f, -TC1, -TSQ, -TS1};
    const float c16x[4] = {1.f, TSQ, 0.f, -TSQ};
    const float c16y[4] = {0.f, -TSQ, -1.f, -TSQ};
    #pragma unroll
    for (int s = 0; s < 16; s += 2) {                // h=1
        f2 u0 = M[s], v0 = M[s + 1];
        M[s] = u0 + v0; M[s + 1] = u0 - v0;
    }
    #pragma unroll
    for (int q = 0; q < 8; ++q) {                    // h=2
        int s = (q & 1) + 4 * (q >> 1);
        f2 u0 = M[s];
        f2 v0 = M[s + 2];
        f2 vw = (s & 1) ? (f2){-v0.y, v0.x} : v0;    // conj(0,-1) = (0,1)
        M[s] = u0 + vw; M[s + 2] = u0 - vw;
    }
    #pragma unroll
    for (int q = 0; q < 8; ++q) {                    // h=4
        int s = (q & 3) + 8 * (q >> 2);
        f2 u0 = M[s];
        f2 vw = cmulcf(M[s + 4], (f2){c16x[s & 3], c16y[s & 3]});
        M[s] = u0 + vw; M[s + 4] = u0 - vw;
    }
    #pragma unroll
    for (int s = 0; s < 8; ++s) {                    // h=8
        f2 u0 = M[s];
        f2 vw = cmulcf(M[s + 8], (f2){c8x[s], c8y[s]});
        M[s] = u0 + vw; M[s + 8] = u0 - vw;
    }
}

__device__ inline void f_rowA(f2* Z, const f2* tw, int tid, int nrows, bool zup) {
    for (int u = tid; u < nrows * 16; u += 1024) {
        int r = u >> 4, b = u & 15;
        f2* row = Z + r * RS;
        f2 L[8];
        #pragma unroll
        for (int s = 0; s < 4; ++s) L[s] = row[17 * s + b];
        if (zup) {
            #pragma unroll
            for (int s = 4; s < 8; ++s) L[s] = (f2){0.f, 0.f};
        } else {
            #pragma unroll
            for (int s = 4; s < 8; ++s) L[s] = row[17 * s + b];
        }
        bflyA_fwd(L, tw, b);
        #pragma unroll
        for (int s = 0; s < 8; ++s) row[17 * s + b] = L[s];
    }
}
__device__ inline void f_rowB(f2* Z, int tid, int nrows) {
    for (int u = tid; u < nrows * 8; u += 1024) {
        int r = u >> 3, g = u & 7;
        f2* blk = Z + r * RS + g * 17;
        f2 M[16];
        #pragma unroll
        for (int s = 0; s < 16; ++s) M[s] = blk[s];
        bfly16_fwd(M);
        #pragma unroll
        for (int s = 0; s < 16; ++s) blk[s] = M[s];
    }
}
__device__ inline void i_rowB(f2* Z, int tid, int nrows) {
    for (int u = tid; u < nrows * 8; u += 1024) {
        int r = u >> 3, g = u & 7;
        f2* blk = Z + r * RS + g * 17;
        f2 M[16];
        #pragma unroll
        for (int s = 0; s < 16; ++s) M[s] = blk[s];
        bfly16_inv(M);
        #pragma unroll
        for (int s = 0; s < 16; ++s) blk[s] = M[s];
    }
}
__device__ inline void f_colA(f2* Z, const f2* tw, int tid, bool zup) {
    for (int u = tid; u < 2048; u += 1024) {
        int c = u >> 4, b = u & 15;
        int cp = cpad(c);
        f2 L[8];
        #pragma unroll
        for (int s = 0; s < 4; ++s) L[s] = Z[(b + 16 * s) * RS + cp];
        if (zup) {
            #pragma unroll
            for (int s = 4; s < 8; ++s) L[s] = (f2){0.f, 0.f};
        } else {
            #pragma unroll
            for (int s = 4; s < 8; ++s) L[s] = Z[(b + 16 * s) * RS + cp];
        }
        bflyA_fwd(L, tw, b);
        #pragma unroll
        for (int s = 0; s < 8; ++s) Z[(b + 16 * s) * RS + cp] = L[s];
    }
}
// i_colA: only rows<64 of the output are consumed downstream -> store s<4.
__device__ inline void i_colA(f2* Z, const f2* tw, int tid) {
    for (int u = tid; u < 2048; u += 1024) {
        int c = u >> 4, b = u & 15;
        int cp = cpad(c);
        f2 L[8];
        #pragma unroll
        for (int s = 0; s < 8; ++s) L[s] = Z[(b + 16 * s) * RS + cp];
        bflyA_inv(L, tw, b);
        #pragma unroll
        for (int s = 0; s < 4; ++s) Z[(b + 16 * s) * RS + cp] = L[s];
    }
}
// colB: lanes span 64 columns (c = tid&127) so banks vary across a wave.
__device__ inline void f_colB(f2* Z, int tid) {        // setup
    int c = tid & 127, g = tid >> 7;
    f2* col = Z + g * 16 * RS + cpad(c);
    f2 M[16];
    #pragma unroll
    for (int s = 0; s < 16; ++s) M[s] = col[s * RS];
    bfly16_fwd(M);
    #pragma unroll
    for (int s = 0; s < 16; ++s) col[s * RS] = M[s];
}
// it_colB: Vf is REAL float (1/16384 pre-folded) — 16 real scales.
__device__ inline void it_colB(f2* Z, const float* Vfg, int tid) {
    int c = tid & 127, g = tid >> 7;
    f2* col = Z + g * 16 * RS + cpad(c);
    const float* vf = Vfg + g * 16 * 128 + c;
    f2 M[16];
    #pragma unroll
    for (int s = 0; s < 16; ++s) M[s] = col[s * RS];
    bfly16_fwd(M);
    #pragma unroll
    for (int s = 0; s < 16; ++s) M[s] = M[s] * f2s(vf[s * 128]);
    bfly16_inv(M);
    #pragma unroll
    for (int s = 0; s < 16; ++s) col[s * RS] = M[s];
}

// One-barrier block reduce: >=1 barrier separates reuses of the same buffer.
__device__ inline double blk_reduce(double v, double* red, int wid, int m) {
    #pragma unroll
    for (int off = 32; off > 0; off >>= 1) v += __shfl_down(v, off);
    if (m == 0) red[wid] = v;
    __syncthreads();
    double s = 0.0;
    #pragma unroll
    for (int i = 0; i < 16; ++i) s += red[i];
    return s;
}

// ---------------------------------------------------------------------------
// k_cg_solve: R17-exact. Thread tid owns elements
//   e_s = (tid>>4)*64 + (tid&15) + 16s  (row r=tid>>4, cols b+16s)
// ---------------------------------------------------------------------------
__global__ __launch_bounds__(1024, 4) void k_cg_solve(
        const float* __restrict__ vcf, float* __restrict__ Vf,
        const double2* __restrict__ rvec, const float* __restrict__ wsv,
        const float* __restrict__ sig2, float* __restrict__ alg)
{
    __shared__ f2 Z[128 * RS];
    __shared__ f2 tw[64];
    __shared__ double redA[16], redB[16], redC[16];

    int tid = threadIdx.x;
    int wid = tid >> 6, m = tid & 63;
    int rr_ = tid >> 4, bb_ = tid & 15;          // this thread's rowA unit

    if (tid < 64) {
        float sn, cs;
        sincospif(-(float)tid / 64.f, &sn, &cs);
        tw[tid] = (f2){cs, sn};
    }
    __syncthreads();

    // ---- Vf setup (forward transform of vc, scrambled order).
    //      Store REAL part only, scaled by 1/16384 (exact pow2).
    for (int i = tid; i < 16384; i += 1024)
        Z[(i >> 7) * RS + cpad(i & 127)] = ((const f2*)vcf)[i];
    __syncthreads();
    f_rowA(Z, tw, tid, 128, false); __syncthreads();
    f_rowB(Z, tid, 128);            __syncthreads();
    f_colA(Z, tw, tid, false);      __syncthreads();
    f_colB(Z, tid);                 __syncthreads();
    for (int i = tid; i < 16384; i += 1024)
        Vf[i] = Z[(i >> 7) * RS + cpad(i & 127)].x * (1.f / 16384.f);
    __syncthreads();

    // ---- CG state (p, r, x all in regs; element e_s = rr_*64 + bb_ + 16s)
    double2 pR[4], rR[4], xR[4];
    float wsr[4];
    double rzp = 0.0;
    #pragma unroll
    for (int s = 0; s < 4; ++s) {
        int e = rr_ * 64 + bb_ + (s << 4);
        double2 bv = rvec[e];
        pR[s] = bv; rR[s] = bv;
        xR[s] = make_double2(0.0, 0.0);
        wsr[s] = wsv[e];
        rzp += bv.x * bv.x + bv.y * bv.y;
    }
    double rz = blk_reduce(rzp, redC, wid, m);
    double s2 = (double)sig2[0];
    __syncthreads();

    for (int it = 0; it < 50; ++it) {
        // ---- fused scatter + forward rowA: z = ws*p from regs (zero-padded)
        {
            f2* row = Z + rr_ * RS;
            f2 L[8];
            #pragma unroll
            for (int s = 0; s < 4; ++s)
                L[s] = (f2){(float)((double)wsr[s] * pR[s].x),
                            (float)((double)wsr[s] * pR[s].y)};
            #pragma unroll
            for (int s = 4; s < 8; ++s) L[s] = (f2){0.f, 0.f};
            bflyA_fwd(L, tw, bb_);
            #pragma unroll
            for (int s = 0; s < 8; ++s) row[17 * s + bb_] = L[s];
        }
        __syncthreads();

        f_rowB(Z, tid, 64);                      __syncthreads();
        f_colA(Z, tw, tid, true);                __syncthreads();
        it_colB(Z, Vf, tid);                     __syncthreads();
        i_colA(Z, tw, tid);                      __syncthreads();
        i_rowB(Z, tid, 64);                      __syncthreads();

        // ---- fused inverse rowA + Ap extraction (L[0..3] are our elements;
        //      unused upper-half outputs dead-code-eliminate).
        //      az is pre-scaled by 1/16384 (folded into Vf).
        f2 az[4];
        {
            f2* row = Z + rr_ * RS;
            f2 L[8];
            #pragma unroll
            for (int s = 0; s < 8; ++s) L[s] = row[17 * s + bb_];
            bflyA_inv(L, tw, bb_);
            #pragma unroll
            for (int s = 0; s < 4; ++s) az[s] = L[s];
        }
        double papp = 0.0;
        #pragma unroll
        for (int s = 0; s < 4; ++s) {
            double apx = (double)wsr[s] * (double)az[s].x + s2 * pR[s].x;
            double apy = (double)wsr[s] * (double)az[s].y + s2 * pR[s].y;
            papp += pR[s].x * apx + pR[s].y * apy;
        }
        double pap = blk_reduce(papp, redA, wid, m);
        double alpha = rz / (pap + 1e-30);

        double rrp = 0.0;
        #pragma unroll
        for (int s = 0; s < 4; ++s) {
            double apx = (double)wsr[s] * (double)az[s].x + s2 * pR[s].x;
            double apy = (double)wsr[s] * (double)az[s].y + s2 * pR[s].y;
            xR[s].x += alpha * pR[s].x; xR[s].y += alpha * pR[s].y;
            rR[s].x -= alpha * apx; rR[s].y -= alpha * apy;
            rrp += rR[s].x * rR[s].x + rR[s].y * rR[s].y;
        }
        double rzn = blk_reduce(rrp, redB, wid, m);
        double beta = rzn / (rz + 1e-30);
        rz = rzn;
        #pragma unroll
        for (int s = 0; s < 4; ++s) {
            pR[s].x = rR[s].x + beta * pR[s].x;
            pR[s].y = rR[s].y + beta * pR[s].y;
        }
    }

    // al = ws * x_50
    #pragma unroll
    for (int s = 0; s < 4; ++s) {
        int e = rr_ * 64 + bb_ + (s << 4);
        ((f2*)alg)[e] = (f2){(float)((double)wsr[s] * xR[s].x),
                             (float)((double)wsr[s] * xR[s].y)};
    }
}

// ---------------------------------------------------------------------------
// k_eval: R17-exact — T1 via fp64 complex recurrence, e2 jg-init hoisted.
// ---------------------------------------------------------------------------
__global__ __launch_bounds__(64) void k_eval(const float* __restrict__ xnew,
                                             const float* __restrict__ alg,
                                             float* __restrict__ out, int B)
{
    __shared__ float2 al[4096];
    int t = threadIdx.x;
    int b = blockIdx.x * 64 + t;
    for (int i = t; i < 4096; i += 64) {
        f2 v = ((const f2*)alg)[i];
        al[i] = make_float2(v.x, v.y);
    }
    float x0 = 0.f, x1 = 0.f;
    if (b < B) { x0 = xnew[2 * b]; x1 = xnew[2 * b + 1]; }
    __syncthreads();
    double2 wstep; { double sn, cs; sincospi((double)x1, &sn, &cs); wstep = make_double2(cs, sn); }
    double2 e2_0;  { double sn, cs; sincospi(-32.0 * (double)x1, &sn, &cs); e2_0 = make_double2(cs, sn); }
    double2 w1;    { double sn, cs; sincospi((double)x0, &sn, &cs); w1 = make_double2(cs, sn); }
    double2 e1;    { double sn, cs; sincospi(-32.0 * (double)x0, &sn, &cs); e1 = make_double2(cs, sn); }
    double mu = 0.0;
    for (int jg = 0; jg < 4; ++jg) {
        float2 tacc[16];
        for (int q = 0; q < 16; ++q) tacc[q] = make_float2(0.f, 0.f);
        double2 e2 = e2_0;
        for (int k = 0; k < 64; ++k) {
            float2 e2f = make_float2((float)e2.x, (float)e2.y);
            for (int q = 0; q < 16; ++q) {
                int j = jg * 16 + q;
                float2 a = al[j * 64 + k];
                tacc[q].x += a.x * e2f.x - a.y * e2f.y;
                tacc[q].y += a.x * e2f.y + a.y * e2f.x;
            }
            e2 = make_double2(e2.x * wstep.x - e2.y * wstep.y,
                              e2.x * wstep.y + e2.y * wstep.x);
        }
        for (int q = 0; q < 16; ++q) {
            mu += e1.x * (double)tacc[q].x - e1.y * (double)tacc[q].y;
            e1 = make_double2(e1.x * w1.x - e1.y * w1.y,
                              e1.x * w1.y + e1.y * w1.x);
        }
    }
    if (b < B) out[b] = (float)mu;
}

// ---------------------------------------------------------------------------

extern "C" void kernel_launch(void* const* d_in, const int* in_sizes, int n_in,
                              void* d_out, int out_size, void* d_ws, size_t ws_size,
                              hipStream_t stream)
{
    const float* x    = (const float*)d_in[0];
    const float* y    = (const float*)d_in[1];
    const float* xnew = (const float*)d_in[2];
    const float* wsv  = (const float*)d_in[3];
    const float* sig2 = (const float*)d_in[4];
    int N = in_sizes[1];
    int B = in_sizes[2] / 2;

    char* base = (char*)d_ws;
    size_t o = 0;
    float*   vcf  = (float*)(base + o);   o += 131072;   // 128x128 circulant vc (fp32)
    float*   Vf   = (float*)(base + o);   o += 65536;    // REAL FFT of vc, /16384 folded
    double2* rvec = (double2*)(base + o); o += 65536;    // b = ws*Fy (fp64)
    float*   alg  = (float*)(base + o);   o += 32768;    // ws*x_50 (fp32 complex)
    size_t avail = (ws_size > o) ? ws_size - o : 0;
    int cv = (int)(avail / 73728);                       // 64KB v-half + 8KB fy per unit
    if (cv > 768) cv = 768;
    if (cv < 16) cv = 16;
    cv &= ~15;
    int cf = cv / 4;
    float* pv = (float*)(base + o); o += (size_t)cv * 65536;
    float* pf = (float*)(base + o);

    hipMemsetAsync(vcf, 0, 131072, stream);              // fp32 atomic target

    k_outer<<<cv + cf, 256, 0, stream>>>(x, y, pv, pf, N, cv, cf);
    k_reduce<<<320, 256, 0, stream>>>(pv, pf, wsv, vcf, rvec, cv, cf);
    k_cg_solve<<<1, 1024, 0, stream>>>(vcf, Vf, rvec, wsv, sig2, alg);
    k_eval<<<(B + 63) / 64, 64, 0, stream>>>(xnew, alg, (float*)d_out, B);
}

// Round 6
// 944.920 us; speedup vs baseline: 1.5489x; 1.2098x over previous
//
#include <hip/hip_runtime.h>
#include <math.h>

// ---------------------------------------------------------------------------
// GP posterior mean:
//   k_outer : R18: half-grid v (conj-symmetric). R19: col-phase LDS layout
//     j-contiguous so h2 loads are 4xb128 instead of 8xb64.
//   k_reduce: R18: writes each half-grid entry + conj mirror.
//   k_cg_solve: R19: CG state in fp32 (reference is complex64 throughout —
//     fp64 state was overkill): p/r/x/ap fp32, per-thread+wave dot partials
//     fp32, cross-wave 16-partial sum fp64, alpha/beta fp64. Halves
//     update-phase issue count, frees ~24 VGPRs (was 48/64 locked).
//     ap cached (was recomputed). R17: Vf REAL fp32 with 1/16384 folded.
//     R16: bfly16 twiddles as local const tables; i_colA half store.
//     R14: CG-state remap; fused scatter+rowA and i_rowA+Ap. 8 barriers/iter.
//     R15 lesson: do NOT hoist arrays into registers (scratch spills).
//   k_eval  : R17-exact: fp64 complex recurrences, 4 sincospi/thread.
// ---------------------------------------------------------------------------

typedef float f2 __attribute__((ext_vector_type(2)));
#define PB 16
#define RS 137          // Z row stride in f2 (8 blocks x 17)

__device__ inline f2 f2s(float s) { return (f2){s, s}; }
__device__ inline f2 cmulf(f2 a, f2 b) {   // a*b
    return (f2){a.x * b.x - a.y * b.y, a.x * b.y + a.y * b.x};
}
__device__ inline f2 cmulcf(f2 a, f2 b) {  // a*conj(b)
    return (f2){a.x * b.x + a.y * b.y, a.y * b.x - a.x * b.y};
}
__device__ inline int cpad(int c) { return (c >> 4) * 17 + (c & 15); }

// exp(i*pi*x*m) with fp64 angle reduction, scaled
__device__ inline f2 phasef(float xv, float m, float scale) {
    double ang = (double)xv * (double)m;
    double r = ang - 2.0 * rint(ang * 0.5);
    float sn, cs;
    sincospif((float)r, &sn, &cs);
    return (f2){cs * scale, sn * scale};
}

// ---------------------------------------------------------------------------
// k_outer: v-part computes HALF grid (rows p1=0..63, cols p2=-63..63).
// LDS layout: hs[p][0..63] = row phases (p1 = t).
//             hs[p][64 + 8*(cc&15) + (cc>>4)] = col phase cc (j-contiguous
//             per tx so h2 loads are 4xb128). cc=127 slot is zero.
// ---------------------------------------------------------------------------
__global__ __launch_bounds__(256, 2) void k_outer(const float* __restrict__ x,
                                                  const float* __restrict__ y,
                                                  float* __restrict__ pv,
                                                  float* __restrict__ pf,
                                                  int N, int cv, int cf)
{
    __shared__ f2 hs[PB][256];
    __shared__ float xs0[PB], xs1[PB], ys[PB];

    int bx = blockIdx.x;
    int t  = threadIdx.x;
    int ty = t >> 4, tx = t & 15;

    if (bx < cv) {
        int CP = (N + cv - 1) / cv;
        int n0 = bx * CP, n1 = min(N, n0 + CP);

        f2 acc[4][8];
        #pragma unroll
        for (int i = 0; i < 4; ++i)
            #pragma unroll
            for (int j = 0; j < 8; ++j) acc[i][j] = (f2){0.f, 0.f};

        for (int s = n0; s < n1; s += PB) {
            int cnt = min(PB, n1 - s);
            __syncthreads();
            if (t < cnt) {
                xs0[t] = x[2 * (s + t)];
                xs1[t] = x[2 * (s + t) + 1];
            }
            __syncthreads();
            for (int p = 0; p < cnt; ++p) {
                if (t < 192) {
                    if (t < 64) {
                        hs[p][t] = phasef(xs0[p], (float)t, 1.f);       // p1 = t
                    } else {
                        int cc = t - 64;                                 // 0..127
                        f2 g = (cc == 127) ? (f2){0.f, 0.f}
                                           : phasef(xs1[p], (float)(cc - 63), 1.f);
                        hs[p][64 + 8 * (cc & 15) + (cc >> 4)] = g;
                    }
                }
            }
            __syncthreads();
            for (int p = 0; p < cnt; ++p) {
                f2 h1[4], h2[8], h2s[8];
                #pragma unroll
                for (int i = 0; i < 4; ++i) h1[i] = hs[p][ty * 4 + i];
                #pragma unroll
                for (int j = 0; j < 8; ++j) {
                    f2 b = hs[p][64 + 8 * tx + j];                       // contiguous
                    h2[j] = b;
                    h2s[j] = (f2){-b.y, b.x};
                }
                #pragma unroll
                for (int i = 0; i < 4; ++i)
                    #pragma unroll
                    for (int j = 0; j < 8; ++j) {
                        acc[i][j] = acc[i][j] + f2s(h1[i].x) * h2[j];
                        acc[i][j] = acc[i][j] + f2s(h1[i].y) * h2s[j];
                    }
            }
        }
        __syncthreads();
        f2* out = (f2*)pv + (size_t)bx * 8192;           // 64x128 f2 = 64KB
        #pragma unroll
        for (int i = 0; i < 4; ++i) {
            int a = ty * 4 + i;
            #pragma unroll
            for (int j = 0; j < 8; ++j)
                out[a * 128 + tx + 16 * j] = acc[i][j];
        }
    } else {
        int chunk = bx - cv;
        int CP = (N + cf - 1) / cf;
        int n0 = chunk * CP, n1 = min(N, n0 + CP);

        f2 acc[4][4];
        #pragma unroll
        for (int i = 0; i < 4; ++i)
            #pragma unroll
            for (int j = 0; j < 4; ++j) acc[i][j] = (f2){0.f, 0.f};

        for (int s = n0; s < n1; s += PB) {
            int cnt = min(PB, n1 - s);
            __syncthreads();
            if (t < cnt) {
                xs0[t] = x[2 * (s + t)];
                xs1[t] = x[2 * (s + t) + 1];
                ys[t]  = y[s + t];
            }
            __syncthreads();
            for (int p2 = 0; p2 < cnt; p2 += 2) {
                int p = p2 + (t >> 7);
                int c = t & 127;
                if (p < cnt) {
                    f2 g;
                    if (c < 64) g = phasef(xs0[p], (float)(32 - c), ys[p]);
                    else        g = phasef(xs1[p], (float)(32 - (c - 64)), 1.f);
                    hs[p][c] = g;
                }
            }
            __syncthreads();
            for (int p = 0; p < cnt; ++p) {
                f2 h1[4], h2[4], h2s[4];
                #pragma unroll
                for (int i = 0; i < 4; ++i) h1[i] = hs[p][ty * 4 + i];
                #pragma unroll
                for (int j = 0; j < 4; ++j) {
                    f2 b = hs[p][64 + tx + 16 * j];
                    h2[j] = b;
                    h2s[j] = (f2){-b.y, b.x};
                }
                #pragma unroll
                for (int i = 0; i < 4; ++i)
                    #pragma unroll
                    for (int j = 0; j < 4; ++j) {
                        acc[i][j] = acc[i][j] + f2s(h1[i].x) * h2[j];
                        acc[i][j] = acc[i][j] + f2s(h1[i].y) * h2s[j];
                    }
            }
        }
        __syncthreads();
        f2* out = (f2*)pf + (size_t)chunk * 4096;
        #pragma unroll
        for (int i = 0; i < 4; ++i) {
            int a = ty * 4 + i;
            #pragma unroll
            for (int j = 0; j < 4; ++j)
                out[a * 64 + tx + 16 * j] = acc[i][j];
        }
    }
}

// ---------------------------------------------------------------------------
// k_reduce: R18. v-part sums the half-grid entry (p1,b) over chunks and
// writes BOTH circulant positions:
//   direct: q1 = p1,        q2 = (b+65)&127,  value (sx,  sy)
//   mirror: q1 = 128-p1,    q2 = (63-b)&127,  value (sx, -sy)   [p1>0 only]
// vcf row/col q=64 stay memset-zero (p1=64 / p2=64 slots, zero as before).
// ---------------------------------------------------------------------------
__global__ __launch_bounds__(256) void k_reduce(const float* __restrict__ pv,
                                                const float* __restrict__ pf,
                                                const float* __restrict__ wsv,
                                                float* __restrict__ vcf,
                                                double2* __restrict__ rvec,
                                                int cv, int cf)
{
    int id = blockIdx.x * 256 + threadIdx.x;
    if (id < 65536) {
        int e = id >> 3, sl = id & 7;        // e: p1 = e>>7 (0..63), b = e&127
        int cn = cv >> 3;
        const float* src = pv + (size_t)e * 2 + (size_t)(sl * cn) * 16384;
        float sx = 0.f, sy = 0.f;
        for (int c = 0; c < cn; ++c) { sx += src[0]; sy += src[1]; src += 16384; }
        int p1 = e >> 7, b = e & 127;
        int q2 = (b + 65) & 127;
        atomicAdd(&vcf[(p1 * 128 + q2) * 2],     sx);
        atomicAdd(&vcf[(p1 * 128 + q2) * 2 + 1], sy);
        if (p1 > 0) {
            int q1m = 128 - p1, q2m = (63 - b) & 127;
            atomicAdd(&vcf[(q1m * 128 + q2m) * 2],     sx);
            atomicAdd(&vcf[(q1m * 128 + q2m) * 2 + 1], -sy);
        }
    } else {
        int e = id - 65536;
        const float* s2p = pf + (size_t)e * 2;
        double fx = 0.0, fy2 = 0.0;
        for (int c = 0; c < cf; ++c) { fx += (double)s2p[0]; fy2 += (double)s2p[1]; s2p += 8192; }
        double w = (double)wsv[e];
        rvec[e] = make_double2(w * fx, w * fy2);
    }
}

// ---------------------------------------------------------------------------
// Fused-stage FFT passes, STATIC register indexing only.
// Z[r*RS + cpad(c)], RS=137. tw[t] = exp(-i*pi*t/64) = W_128^t.
// bfly16 twiddles are lane-uniform -> LOCAL const tables (SROA-folded to
// immediates after unroll; no LDS / no constant-mem traffic).
// ---------------------------------------------------------------------------
#define TC1 0.92387953251128676f   // cos(pi/8)
#define TS1 0.38268343236508977f   // sin(pi/8)
#define TSQ 0.70710678118654752f   // sqrt(2)/2

__device__ inline void bflyA_fwd(f2* L, const f2* tw, int b) {
    #pragma unroll
    for (int s = 0; s < 4; ++s) {                    // h=64
        f2 u0 = L[s], v0 = L[s + 4];
        L[s] = u0 + v0;
        L[s + 4] = cmulf(u0 - v0, tw[b + 16 * s]);
    }
    const int ss[4] = {0, 1, 4, 5};
    #pragma unroll
    for (int q = 0; q < 4; ++q) {                    // h=32
        int s = ss[q];
        f2 u0 = L[s], v0 = L[s + 2];
        L[s] = u0 + v0;
        L[s + 2] = cmulf(u0 - v0, tw[2 * b + 32 * (s & 1)]);
    }
    #pragma unroll
    for (int s = 0; s < 8; s += 2) {                 // h=16
        f2 u0 = L[s], v0 = L[s + 1];
        L[s] = u0 + v0;
        L[s + 1] = cmulf(u0 - v0, tw[4 * b]);
    }
}
__device__ inline void bflyA_inv(f2* L, const f2* tw, int b) {
    #pragma unroll
    for (int s = 0; s < 8; s += 2) {                 // h=16
        f2 u0 = L[s];
        f2 vw = cmulcf(L[s + 1], tw[4 * b]);
        L[s] = u0 + vw; L[s + 1] = u0 - vw;
    }
    const int ss[4] = {0, 1, 4, 5};
    #pragma unroll
    for (int q = 0; q < 4; ++q) {                    // h=32
        int s = ss[q];
        f2 u0 = L[s];
        f2 vw = cmulcf(L[s + 2], tw[2 * b + 32 * (s & 1)]);
        L[s] = u0 + vw; L[s + 2] = u0 - vw;
    }
    #pragma unroll
    for (int s = 0; s < 4; ++s) {                    // h=64
        f2 u0 = L[s];
        f2 vw = cmulcf(L[s + 4], tw[b + 16 * s]);
        L[s] = u0 + vw; L[s + 4] = u0 - vw;
    }
}
__device__ inline void bfly16_fwd(f2* M) {
    const float c8x[8]  = {1.f, TC1, TSQ, TS1, 0.f, -TS1, -TSQ, -TC1};
    const float c8y[8]  = {0.f, -TS1, -TSQ, -TC1, -1.f, -TC1, -TSQ, -TS1};
    const float c16x[4] = {1.f, TSQ, 0.f, -TSQ};
    const float c16y[4] = {0.f, -TSQ, -1.f, -TSQ};
    #pragma unroll
    for (int s = 0; s < 8; ++s) {                    // h=8
        f2 u0 = M[s], v0 = M[s + 8];
        M[s] = u0 + v0;
        M[s + 8] = cmulf(u0 - v0, (f2){c8x[s], c8y[s]});
    }
    #pragma unroll
    for (int q = 0; q < 8; ++q) {                    // h=4
        int s = (q & 3) + 8 * (q >> 2);
        f2 u0 = M[s], v0 = M[s + 4];
        M[s] = u0 + v0;
        M[s + 4] = cmulf(u0 - v0, (f2){c16x[s & 3], c16y[s & 3]});
    }
    #pragma unroll
    for (int q = 0; q < 8; ++q) {                    // h=2
        int s = (q & 1) + 4 * (q >> 1);
        f2 u0 = M[s], v0 = M[s + 2];
        M[s] = u0 + v0;
        f2 d = u0 - v0;
        M[s + 2] = (s & 1) ? (f2){d.y, -d.x} : d;    // * (0,-1) or * 1
    }
    #pragma unroll
    for (int s = 0; s < 16; s += 2) {                // h=1
        f2 u0 = M[s], v0 = M[s + 1];
        M[s] = u0 + v0; M[s + 1] = u0 - v0;
    }
}
__device__ inline void bfly16_inv(f2* M) {
    const float c8x[8]  = {1.f, TC1, TSQ, TS1, 0.f, -TS1, -TSQ, -TC1};
    const float c8y[8]  = {0.f, -TS1, -TSQ, -TC1, -1.f, -TC1, -TSQ, -TS1};
    const float c16x[4] = {1.f, TSQ, 0.f, -TSQ};
    const float c16y[4] = {0.f, -TSQ, -1.f, -TSQ};
    #pragma unroll
    for (int s = 0; s < 16; s += 2) {                // h=1
        f2 u0 = M[s], v0 = M[s + 1];
        M[s] = u0 + v0; M[s + 1] = u0 - v0;
    }
    #pragma unroll
    for (int q = 0; q < 8; ++q) {                    // h=2
        int s = (q & 1) + 4 * (q >> 1);
        f2 u0 = M[s];
        f2 v0 = M[s + 2];
        f2 vw = (s & 1) ? (f2){-v0.y, v0.x} : v0;    // conj(0,-1) = (0,1)
        M[s] = u0 + vw; M[s + 2] = u0 - vw;
    }
    #pragma unroll
    for (int q = 0; q < 8; ++q) {                    // h=4
        int s = (q & 3) + 8 * (q >> 2);
        f2 u0 = M[s];
        f2 vw = cmulcf(M[s + 4], (f2){c16x[s & 3], c16y[s & 3]});
        M[s] = u0 + vw; M[s + 4] = u0 - vw;
    }
    #pragma unroll
    for (int s = 0; s < 8; ++s) {                    // h=8
        f2 u0 = M[s];
        f2 vw = cmulcf(M[s + 8], (f2){c8x[s], c8y[s]});
        M[s] = u0 + vw; M[s + 8] = u0 - vw;
    }
}

__device__ inline void f_rowA(f2* Z, const f2* tw, int tid, int nrows, bool zup) {
    for (int u = tid; u < nrows * 16; u += 1024) {
        int r = u >> 4, b = u & 15;
        f2* row = Z + r * RS;
        f2 L[8];
        #pragma unroll
        for (int s = 0; s < 4; ++s) L[s] = row[17 * s + b];
        if (zup) {
            #pragma unroll
            for (int s = 4; s < 8; ++s) L[s] = (f2){0.f, 0.f};
        } else {
            #pragma unroll
            for (int s = 4; s < 8; ++s) L[s] = row[17 * s + b];
        }
        bflyA_fwd(L, tw, b);
        #pragma unroll
        for (int s = 0; s < 8; ++s) row[17 * s + b] = L[s];
    }
}
__device__ inline void f_rowB(f2* Z, int tid, int nrows) {
    for (int u = tid; u < nrows * 8; u += 1024) {
        int r = u >> 3, g = u & 7;
        f2* blk = Z + r * RS + g * 17;
        f2 M[16];
        #pragma unroll
        for (int s = 0; s < 16; ++s) M[s] = blk[s];
        bfly16_fwd(M);
        #pragma unroll
        for (int s = 0; s < 16; ++s) blk[s] = M[s];
    }
}
__device__ inline void i_rowB(f2* Z, int tid, int nrows) {
    for (int u = tid; u < nrows * 8; u += 1024) {
        int r = u >> 3, g = u & 7;
        f2* blk = Z + r * RS + g * 17;
        f2 M[16];
        #pragma unroll
        for (int s = 0; s < 16; ++s) M[s] = blk[s];
        bfly16_inv(M);
        #pragma unroll
        for (int s = 0; s < 16; ++s) blk[s] = M[s];
    }
}
__device__ inline void f_colA(f2* Z, const f2* tw, int tid, bool zup) {
    for (int u = tid; u < 2048; u += 1024) {
        int c = u >> 4, b = u & 15;
        int cp = cpad(c);
        f2 L[8];
        #pragma unroll
        for (int s = 0; s < 4; ++s) L[s] = Z[(b + 16 * s) * RS + cp];
        if (zup) {
            #pragma unroll
            for (int s = 4; s < 8; ++s) L[s] = (f2){0.f, 0.f};
        } else {
            #pragma unroll
            for (int s = 4; s < 8; ++s) L[s] = Z[(b + 16 * s) * RS + cp];
        }
        bflyA_fwd(L, tw, b);
        #pragma unroll
        for (int s = 0; s < 8; ++s) Z[(b + 16 * s) * RS + cp] = L[s];
    }
}
// i_colA: only rows<64 of the output are consumed downstream -> store s<4.
__device__ inline void i_colA(f2* Z, const f2* tw, int tid) {
    for (int u = tid; u < 2048; u += 1024) {
        int c = u >> 4, b = u & 15;
        int cp = cpad(c);
        f2 L[8];
        #pragma unroll
        for (int s = 0; s < 8; ++s) L[s] = Z[(b + 16 * s) * RS + cp];
        bflyA_inv(L, tw, b);
        #pragma unroll
        for (int s = 0; s < 4; ++s) Z[(b + 16 * s) * RS + cp] = L[s];
    }
}
// colB: lanes span 64 columns (c = tid&127) so banks vary across a wave.
__device__ inline void f_colB(f2* Z, int tid) {        // setup
    int c = tid & 127, g = tid >> 7;
    f2* col = Z + g * 16 * RS + cpad(c);
    f2 M[16];
    #pragma unroll
    for (int s = 0; s < 16; ++s) M[s] = col[s * RS];
    bfly16_fwd(M);
    #pragma unroll
    for (int s = 0; s < 16; ++s) col[s * RS] = M[s];
}
// it_colB: Vf is REAL float (1/16384 pre-folded) — 16 real scales.
__device__ inline void it_colB(f2* Z, const float* Vfg, int tid) {
    int c = tid & 127, g = tid >> 7;
    f2* col = Z + g * 16 * RS + cpad(c);
    const float* vf = Vfg + g * 16 * 128 + c;
    f2 M[16];
    #pragma unroll
    for (int s = 0; s < 16; ++s) M[s] = col[s * RS];
    bfly16_fwd(M);
    #pragma unroll
    for (int s = 0; s < 16; ++s) M[s] = M[s] * f2s(vf[s * 128]);
    bfly16_inv(M);
    #pragma unroll
    for (int s = 0; s < 16; ++s) col[s * RS] = M[s];
}

// Reduce helpers: >=1 barrier separates reuses of the same buffer.
__device__ inline double blk_reduce(double v, double* red, int wid, int m) {
    #pragma unroll
    for (int off = 32; off > 0; off >>= 1) v += __shfl_down(v, off);
    if (m == 0) red[wid] = v;
    __syncthreads();
    double s = 0.0;
    #pragma unroll
    for (int i = 0; i < 16; ++i) s += red[i];
    return s;
}
// fp32 in-wave reduce, fp64 across the 16 wave partials.
__device__ inline double blk_reduce_f(float v, double* red, int wid, int m) {
    #pragma unroll
    for (int off = 32; off > 0; off >>= 1) v += __shfl_down(v, off);
    if (m == 0) red[wid] = (double)v;
    __syncthreads();
    double s = 0.0;
    #pragma unroll
    for (int i = 0; i < 16; ++i) s += red[i];
    return s;
}

// ---------------------------------------------------------------------------
// k_cg_solve: R19 (fp32 CG state). Thread tid owns elements
//   e_s = (tid>>4)*64 + (tid&15) + 16s  (row r=tid>>4, cols b+16s)
// ---------------------------------------------------------------------------
__global__ __launch_bounds__(1024, 4) void k_cg_solve(
        const float* __restrict__ vcf, float* __restrict__ Vf,
        const double2* __restrict__ rvec, const float* __restrict__ wsv,
        const float* __restrict__ sig2, float* __restrict__ alg)
{
    __shared__ f2 Z[128 * RS];
    __shared__ f2 tw[64];
    __shared__ double redA[16], redB[16], redC[16];

    int tid = threadIdx.x;
    int wid = tid >> 6, m = tid & 63;
    int rr_ = tid >> 4, bb_ = tid & 15;          // this thread's rowA unit

    if (tid < 64) {
        float sn, cs;
        sincospif(-(float)tid / 64.f, &sn, &cs);
        tw[tid] = (f2){cs, sn};
    }
    __syncthreads();

    // ---- Vf setup (forward transform of vc, scrambled order).
    //      Store REAL part only, scaled by 1/16384 (exact pow2).
    for (int i = tid; i < 16384; i += 1024)
        Z[(i >> 7) * RS + cpad(i & 127)] = ((const f2*)vcf)[i];
    __syncthreads();
    f_rowA(Z, tw, tid, 128, false); __syncthreads();
    f_rowB(Z, tid, 128);            __syncthreads();
    f_colA(Z, tw, tid, false);      __syncthreads();
    f_colB(Z, tid);                 __syncthreads();
    for (int i = tid; i < 16384; i += 1024)
        Vf[i] = Z[(i >> 7) * RS + cpad(i & 127)].x * (1.f / 16384.f);
    __syncthreads();

    // ---- CG state, fp32 (reference is complex64 end-to-end).
    f2 pR[4], rR[4], xR[4];
    float wsr[4];
    float rzp = 0.f;
    #pragma unroll
    for (int s = 0; s < 4; ++s) {
        int e = rr_ * 64 + bb_ + (s << 4);
        double2 bv = rvec[e];
        f2 bf = (f2){(float)bv.x, (float)bv.y};
        pR[s] = bf; rR[s] = bf;
        xR[s] = (f2){0.f, 0.f};
        wsr[s] = wsv[e];
        rzp += bf.x * bf.x + bf.y * bf.y;
    }
    double rz = blk_reduce_f(rzp, redC, wid, m);
    float s2f = sig2[0];
    __syncthreads();

    for (int it = 0; it < 50; ++it) {
        // ---- fused scatter + forward rowA: z = ws*p from regs (zero-padded)
        {
            f2* row = Z + rr_ * RS;
            f2 L[8];
            #pragma unroll
            for (int s = 0; s < 4; ++s) L[s] = f2s(wsr[s]) * pR[s];
            #pragma unroll
            for (int s = 4; s < 8; ++s) L[s] = (f2){0.f, 0.f};
            bflyA_fwd(L, tw, bb_);
            #pragma unroll
            for (int s = 0; s < 8; ++s) row[17 * s + bb_] = L[s];
        }
        __syncthreads();

        f_rowB(Z, tid, 64);                      __syncthreads();
        f_colA(Z, tw, tid, true);                __syncthreads();
        it_colB(Z, Vf, tid);                     __syncthreads();
        i_colA(Z, tw, tid);                      __syncthreads();
        i_rowB(Z, tid, 64);                      __syncthreads();

        // ---- fused inverse rowA + Ap (az pre-scaled by 1/16384 via Vf)
        f2 ap[4];
        float papp = 0.f;
        {
            f2* row = Z + rr_ * RS;
            f2 L[8];
            #pragma unroll
            for (int s = 0; s < 8; ++s) L[s] = row[17 * s + bb_];
            bflyA_inv(L, tw, bb_);
            #pragma unroll
            for (int s = 0; s < 4; ++s) {
                ap[s].x = wsr[s] * L[s].x + s2f * pR[s].x;
                ap[s].y = wsr[s] * L[s].y + s2f * pR[s].y;
                papp += pR[s].x * ap[s].x + pR[s].y * ap[s].y;
            }
        }
        double pap = blk_reduce_f(papp, redA, wid, m);
        float alpha = (float)(rz / (pap + 1e-30));

        float rrp = 0.f;
        #pragma unroll
        for (int s = 0; s < 4; ++s) {
            xR[s] = xR[s] + f2s(alpha) * pR[s];
            rR[s] = rR[s] - f2s(alpha) * ap[s];
            rrp += rR[s].x * rR[s].x + rR[s].y * rR[s].y;
        }
        double rzn = blk_reduce_f(rrp, redB, wid, m);
        float beta = (float)(rzn / (rz + 1e-30));
        rz = rzn;
        #pragma unroll
        for (int s = 0; s < 4; ++s)
            pR[s] = rR[s] + f2s(beta) * pR[s];
    }

    // al = ws * x_50
    #pragma unroll
    for (int s = 0; s < 4; ++s) {
        int e = rr_ * 64 + bb_ + (s << 4);
        ((f2*)alg)[e] = f2s(wsr[s]) * xR[s];
    }
}

// ---------------------------------------------------------------------------
// k_eval: R17-exact — T1 via fp64 complex recurrence, e2 jg-init hoisted.
// ---------------------------------------------------------------------------
__global__ __launch_bounds__(64) void k_eval(const float* __restrict__ xnew,
                                             const float* __restrict__ alg,
                                             float* __restrict__ out, int B)
{
    __shared__ float2 al[4096];
    int t = threadIdx.x;
    int b = blockIdx.x * 64 + t;
    for (int i = t; i < 4096; i += 64) {
        f2 v = ((const f2*)alg)[i];
        al[i] = make_float2(v.x, v.y);
    }
    float x0 = 0.f, x1 = 0.f;
    if (b < B) { x0 = xnew[2 * b]; x1 = xnew[2 * b + 1]; }
    __syncthreads();
    double2 wstep; { double sn, cs; sincospi((double)x1, &sn, &cs); wstep = make_double2(cs, sn); }
    double2 e2_0;  { double sn, cs; sincospi(-32.0 * (double)x1, &sn, &cs); e2_0 = make_double2(cs, sn); }
    double2 w1;    { double sn, cs; sincospi((double)x0, &sn, &cs); w1 = make_double2(cs, sn); }
    double2 e1;    { double sn, cs; sincospi(-32.0 * (double)x0, &sn, &cs); e1 = make_double2(cs, sn); }
    double mu = 0.0;
    for (int jg = 0; jg < 4; ++jg) {
        float2 tacc[16];
        for (int q = 0; q < 16; ++q) tacc[q] = make_float2(0.f, 0.f);
        double2 e2 = e2_0;
        for (int k = 0; k < 64; ++k) {
            float2 e2f = make_float2((float)e2.x, (float)e2.y);
            for (int q = 0; q < 16; ++q) {
                int j = jg * 16 + q;
                float2 a = al[j * 64 + k];
                tacc[q].x += a.x * e2f.x - a.y * e2f.y;
                tacc[q].y += a.x * e2f.y + a.y * e2f.x;
            }
            e2 = make_double2(e2.x * wstep.x - e2.y * wstep.y,
                              e2.x * wstep.y + e2.y * wstep.x);
        }
        for (int q = 0; q < 16; ++q) {
            mu += e1.x * (double)tacc[q].x - e1.y * (double)tacc[q].y;
            e1 = make_double2(e1.x * w1.x - e1.y * w1.y,
                              e1.x * w1.y + e1.y * w1.x);
        }
    }
    if (b < B) out[b] = (float)mu;
}

// ---------------------------------------------------------------------------

extern "C" void kernel_launch(void* const* d_in, const int* in_sizes, int n_in,
                              void* d_out, int out_size, void* d_ws, size_t ws_size,
                              hipStream_t stream)
{
    const float* x    = (const float*)d_in[0];
    const float* y    = (const float*)d_in[1];
    const float* xnew = (const float*)d_in[2];
    const float* wsv  = (const float*)d_in[3];
    const float* sig2 = (const float*)d_in[4];
    int N = in_sizes[1];
    int B = in_sizes[2] / 2;

    char* base = (char*)d_ws;
    size_t o = 0;
    float*   vcf  = (float*)(base + o);   o += 131072;   // 128x128 circulant vc (fp32)
    float*   Vf   = (float*)(base + o);   o += 65536;    // REAL FFT of vc, /16384 folded
    double2* rvec = (double2*)(base + o); o += 65536;    // b = ws*Fy (fp64)
    float*   alg  = (float*)(base + o);   o += 32768;    // ws*x_50 (fp32 complex)
    size_t avail = (ws_size > o) ? ws_size - o : 0;
    int cv = (int)(avail / 73728);                       // 64KB v-half + 8KB fy per unit
    if (cv > 768) cv = 768;
    if (cv < 16) cv = 16;
    cv &= ~15;
    int cf = cv / 4;
    float* pv = (float*)(base + o); o += (size_t)cv * 65536;
    float* pf = (float*)(base + o);

    hipMemsetAsync(vcf, 0, 131072, stream);              // fp32 atomic target

    k_outer<<<cv + cf, 256, 0, stream>>>(x, y, pv, pf, N, cv, cf);
    k_reduce<<<320, 256, 0, stream>>>(pv, pf, wsv, vcf, rvec, cv, cf);
    k_cg_solve<<<1, 1024, 0, stream>>>(vcf, Vf, rvec, wsv, sig2, alg);
    k_eval<<<(B + 63) / 64, 64, 0, stream>>>(xnew, alg, (float*)d_out, B);
}